// Round 1
// baseline (420.840 us; speedup 1.0000x reference)
//
#include <hip/hip_runtime.h>

// NTK-SVGP forward: D=H=128, C=10, N=256, M=128, T=128, sigma2=1, delta=1
#define H 128
#define DD 128
#define CC 10
#define NX 256
#define MZ 128
#define TN 128
#define S_TOT 512   // samples: X[0..255], Z[256..383], X_test[384..511]
#define SCALE (1.0f/256.0f)   // 1/(delta*N)
#define JIT 1e-3f
#define INV_S2 1.0f

// ---------------- ws layout (float offsets) ----------------
#define OFF_XS    0u
#define OFF_A1    (OFF_XS   + S_TOT*DD)          // 65536
#define OFF_A2    (OFF_A1   + S_TOT*H)
#define OFF_G1    (OFF_A2   + S_TOT*H)
#define OFF_G2    (OFF_G1   + S_TOT*CC*H)
#define OFF_W2T   (OFF_G2   + S_TOT*CC*H)
#define OFF_BASE  (OFF_W2T  + H*H)
#define BASE_ZX   0u
#define BASE_ZZ   (3u*MZ*NX)
#define BASE_TZ   (3u*MZ*NX + 3u*MZ*MZ)
#define OFF_KZX   (OFF_BASE + 3u*MZ*NX + 3u*MZ*MZ + 3u*TN*MZ)
#define OFF_KZZ   (OFF_KZX  + CC*MZ*NX)
#define OFF_KXZ   (OFF_KZZ  + CC*MZ*MZ)
#define OFF_KXXD  (OFF_KXZ  + CC*TN*MZ)
#define OFF_KZZJ  (OFF_KXXD + CC*TN)
#define OFF_KZZB  (OFF_KZZJ + CC*MZ*MZ)
#define OFF_LAMU  (OFF_KZZB + CC*MZ*MZ)
#define OFF_LC    (OFF_LAMU + CC*MZ)
#define OFF_LR    (OFF_LC   + 2u*CC*MZ*MZ)
#define OFF_INVD  (OFF_LR   + 2u*CC*MZ*MZ)
#define OFF_YLAM  (OFF_INVD + 2u*CC*MZ)
#define OFF_SSQ   (OFF_YLAM + CC*MZ)
#define OFF_FMEAN (OFF_SSQ  + 2u*CC*TN)
// total = OFF_FMEAN + CC*TN  ~ 3.37M floats ~ 12.9 MB

__global__ __launch_bounds__(128) void k_w2t(const float* __restrict__ W2, float* __restrict__ W2T) {
  int k = blockIdx.x, h = threadIdx.x;
  W2T[k*H + h] = W2[h*H + k];
}

// Per-sample forward + backprop features. One block per sample, 128 threads.
__global__ __launch_bounds__(128) void k_features(
    const float* __restrict__ X, const float* __restrict__ Z, const float* __restrict__ Xt,
    const float* __restrict__ W1, const float* __restrict__ b1,
    const float* __restrict__ W2, const float* __restrict__ b2,
    const float* __restrict__ W3, const float* __restrict__ W2T,
    float* __restrict__ XS, float* __restrict__ A1, float* __restrict__ A2,
    float* __restrict__ G1, float* __restrict__ G2)
{
  int s = blockIdx.x, h = threadIdx.x;
  const float* xin = (s < NX) ? X + s*DD : (s < NX+MZ ? Z + (s-NX)*DD : Xt + (s-NX-MZ)*DD);
  __shared__ float xs[DD], a1s[H], g2s[CC*H];
  float xv = xin[h];
  xs[h] = xv; XS[s*DD + h] = xv;
  __syncthreads();
  float acc = b1[h];
  #pragma unroll 4
  for (int d0 = 0; d0 < DD; ++d0) acc += xs[d0] * W1[d0*H + h];   // coalesced over h
  float a1 = tanhf(acc);
  a1s[h] = a1; A1[s*H + h] = a1;
  __syncthreads();
  acc = b2[h];
  #pragma unroll 4
  for (int d0 = 0; d0 < H; ++d0) acc += a1s[d0] * W2[d0*H + h];
  float a2 = tanhf(acc);
  A2[s*H + h] = a2;
  float t2 = 1.0f - a2*a2;
  #pragma unroll
  for (int c = 0; c < CC; ++c) {
    float g2 = W3[h*CC + c] * t2;
    g2s[c*H + h] = g2;
    G2[(s*CC + c)*H + h] = g2;
  }
  __syncthreads();
  float t1 = 1.0f - a1*a1;
  float accs[CC];
  #pragma unroll
  for (int c = 0; c < CC; ++c) accs[c] = 0.0f;
  for (int k = 0; k < H; ++k) {
    float w = W2T[k*H + h];        // coalesced over h
    #pragma unroll
    for (int c = 0; c < CC; ++c) accs[c] += w * g2s[c*H + k];   // broadcast
  }
  #pragma unroll
  for (int c = 0; c < CC; ++c) G1[(s*CC + c)*H + h] = t1 * accs[c];
}

// Class-independent base dot products: 1+x.x', 1+a1.a1', 1+a2.a2'
// grid (ntile<=16, mtile=8, set in {0:ZX,1:ZZ,2:TZ}), 256 threads = 16x16 tile.
__global__ __launch_bounds__(256) void k_base(const float* __restrict__ XS,
    const float* __restrict__ A1, const float* __restrict__ A2, float* __restrict__ Base)
{
  int set = blockIdx.z;
  int colsN = (set == 0) ? NX : MZ;
  if ((int)blockIdx.x * 16 >= colsN) return;
  int rowOff = (set == 2) ? NX+MZ : NX;
  int colOff = (set == 0) ? 0 : NX;
  unsigned baseOff = (set == 0) ? BASE_ZX : (set == 1 ? BASE_ZZ : BASE_TZ);
  __shared__ float rx[16*132], r1[16*132], r2[16*132], cxs[16*132], c1s[16*132], c2s[16*132];
  int tid = threadIdx.x, m0 = blockIdx.y*16, n0 = blockIdx.x*16;
  for (int idx = tid; idx < 16*128; idx += 256) {
    int r = idx >> 7, hh = idx & 127;
    int sr = rowOff + m0 + r, sc = colOff + n0 + r;
    rx [r*132+hh] = XS[sr*DD+hh]; r1[r*132+hh] = A1[sr*H+hh]; r2[r*132+hh] = A2[sr*H+hh];
    cxs[r*132+hh] = XS[sc*DD+hh]; c1s[r*132+hh] = A1[sc*H+hh]; c2s[r*132+hh] = A2[sc*H+hh];
  }
  __syncthreads();
  int ty = tid >> 4, tx = tid & 15;
  const float4* pa = (const float4*)(rx  + ty*132);
  const float4* pb = (const float4*)(cxs + tx*132);
  const float4* pc = (const float4*)(r1  + ty*132);
  const float4* pd = (const float4*)(c1s + tx*132);
  const float4* pe = (const float4*)(r2  + ty*132);
  const float4* pf = (const float4*)(c2s + tx*132);
  float d0 = 0, d1 = 0, d2 = 0;
  #pragma unroll 8
  for (int q = 0; q < 32; ++q) {
    float4 a = pa[q], b = pb[q]; d0 += a.x*b.x + a.y*b.y + a.z*b.z + a.w*b.w;
    float4 c = pc[q], d = pd[q]; d1 += c.x*d.x + c.y*d.y + c.z*d.z + c.w*d.w;
    float4 e = pe[q], f = pf[q]; d2 += e.x*f.x + e.y*f.y + e.z*f.z + e.w*f.w;
  }
  int m = m0 + ty, n = n0 + tx;
  float* Bp = Base + baseOff;
  int area = 128 * colsN;
  Bp[0*area + m*colsN + n] = 1.0f + d0;
  Bp[1*area + m*colsN + n] = 1.0f + d1;
  Bp[2*area + m*colsN + n] = 1.0f + d2;
}

// Per-class NTK gram: K = SCALE*(B0*(g1.g1') + B1*(g2.g2') + B2)
// grid (ntile<=16, mtile=8, set*10+c), 256 threads.
__global__ __launch_bounds__(256) void k_gram(const float* __restrict__ G1, const float* __restrict__ G2,
    const float* __restrict__ Base, float* __restrict__ Kzx, float* __restrict__ Kzz, float* __restrict__ Kxz)
{
  int z = blockIdx.z, set = z / CC, c = z % CC;
  int colsN = (set == 0) ? NX : MZ;
  if ((int)blockIdx.x * 16 >= colsN) return;
  int rowOff = (set == 2) ? NX+MZ : NX;
  int colOff = (set == 0) ? 0 : NX;
  unsigned baseOff = (set == 0) ? BASE_ZX : (set == 1 ? BASE_ZZ : BASE_TZ);
  float* outp = (set == 0) ? Kzx + c*MZ*NX : (set == 1 ? Kzz + c*MZ*MZ : Kxz + c*TN*MZ);
  __shared__ float g1r[16*132], g2r[16*132], g1c[16*132], g2c[16*132];
  int tid = threadIdx.x, m0 = blockIdx.y*16, n0 = blockIdx.x*16;
  for (int idx = tid; idx < 2048; idx += 256) {
    int r = idx >> 7, hh = idx & 127;
    int sr = rowOff + m0 + r, sc = colOff + n0 + r;
    g1r[r*132+hh] = G1[(sr*CC + c)*H + hh]; g2r[r*132+hh] = G2[(sr*CC + c)*H + hh];
    g1c[r*132+hh] = G1[(sc*CC + c)*H + hh]; g2c[r*132+hh] = G2[(sc*CC + c)*H + hh];
  }
  __syncthreads();
  int ty = tid >> 4, tx = tid & 15;
  const float4* p1 = (const float4*)(g1r + ty*132);
  const float4* p2 = (const float4*)(g1c + tx*132);
  const float4* p3 = (const float4*)(g2r + ty*132);
  const float4* p4 = (const float4*)(g2c + tx*132);
  float dg1 = 0, dg2 = 0;
  #pragma unroll 8
  for (int q = 0; q < 32; ++q) {
    float4 a = p1[q], b = p2[q]; dg1 += a.x*b.x + a.y*b.y + a.z*b.z + a.w*b.w;
    float4 e = p3[q], f = p4[q]; dg2 += e.x*f.x + e.y*f.y + e.z*f.z + e.w*f.w;
  }
  int m = m0 + ty, n = n0 + tx;
  const float* Bp = Base + baseOff;
  int area = 128 * colsN;
  float b0 = Bp[m*colsN + n], b1v = Bp[area + m*colsN + n], b2v = Bp[2*area + m*colsN + n];
  outp[m*colsN + n] = SCALE * (b0*dg1 + b1v*dg2 + b2v);
}

__device__ __forceinline__ float blockReduce128(float v, float* red, int h) {
  #pragma unroll
  for (int off = 32; off > 0; off >>= 1) v += __shfl_down(v, off, 64);
  if ((h & 63) == 0) red[h >> 6] = v;
  __syncthreads();
  float r = red[0] + red[1];
  __syncthreads();
  return r;
}

// Kxx_diag[c][t]; one block per test sample.
__global__ __launch_bounds__(128) void k_kxxd(const float* __restrict__ XS, const float* __restrict__ A1,
    const float* __restrict__ A2, const float* __restrict__ G1, const float* __restrict__ G2,
    float* __restrict__ Kxxd)
{
  int t = blockIdx.x, h = threadIdx.x, s = NX + MZ + t;
  __shared__ float red[2];
  float xv = XS[s*DD+h], a1v = A1[s*H+h], a2v = A2[s*H+h];
  float nx  = blockReduce128(xv*xv,  red, h);
  float na1 = blockReduce128(a1v*a1v, red, h);
  float na2 = blockReduce128(a2v*a2v, red, h);
  for (int c = 0; c < CC; ++c) {
    float g1 = G1[(s*CC+c)*H+h], g2 = G2[(s*CC+c)*H+h];
    float n1 = blockReduce128(g1*g1, red, h);
    float n2 = blockReduce128(g2*g2, red, h);
    if (h == 0) Kxxd[c*TN + t] = SCALE * ((1.0f+nx)*n1 + (1.0f+na1)*n2 + (1.0f+na2));
  }
}

// KzzB = Kzz + Kzx Kzx^T / sigma2 + 2*JIT*I ; Kzzj = Kzz + JIT*I
__global__ __launch_bounds__(256) void k_kzzb(const float* __restrict__ Kzx, const float* __restrict__ Kzz,
    float* __restrict__ Kzzj, float* __restrict__ KzzB)
{
  int c = blockIdx.z, m0 = blockIdx.y*16, k0 = blockIdx.x*16;
  int tid = threadIdx.x, ty = tid >> 4, tx = tid & 15;
  __shared__ float Am[16*17], Ak[16*17];
  const float* Kc = Kzx + c*MZ*NX;
  float acc = 0;
  for (int nc = 0; nc < NX; nc += 16) {
    Am[ty*17+tx] = Kc[(m0+ty)*NX + nc + tx];
    Ak[ty*17+tx] = Kc[(k0+ty)*NX + nc + tx];
    __syncthreads();
    #pragma unroll
    for (int p = 0; p < 16; ++p) acc += Am[ty*17+p] * Ak[tx*17+p];
    __syncthreads();
  }
  int m = m0+ty, k = k0+tx, idx = c*MZ*MZ + m*MZ + k;
  float kzz = Kzz[idx];
  float dia = (m == k) ? 1.0f : 0.0f;
  Kzzj[idx] = kzz + dia*JIT;
  KzzB[idx] = kzz + acc*INV_S2 + dia*2.0f*JIT;
}

// Lambda_u[c][m] = sum_n Kzx[c][m][n] * Y[n][c] / sigma2   (Lam = Y/sigma2; F cancels)
__global__ __launch_bounds__(128) void k_lambda(const float* __restrict__ Kzx, const float* __restrict__ Y,
    float* __restrict__ LamU)
{
  int c = blockIdx.x, m = threadIdx.x;
  const float* Kc = Kzx + c*MZ*NX + m*NX;
  float acc = 0;
  for (int n = 0; n < NX; ++n) acc += Kc[n] * Y[n*CC + c];
  LamU[c*MZ + m] = acc * INV_S2;
}

// Blocked (rank-4) Cholesky, in-LDS, column-major. Writes Lc (col-major), Lr (row-major), invd.
// grid: 20 blocks (c,which), 256 threads.
__global__ __launch_bounds__(256) void k_chol(const float* __restrict__ Kzzj, const float* __restrict__ KzzB,
    float* __restrict__ Lc, float* __restrict__ Lr, float* __restrict__ invd)
{
  int which = blockIdx.x & 1, c = blockIdx.x >> 1;
  const float* Ain = (which ? KzzB : Kzzj) + c*MZ*MZ;
  float* LcB = Lc + (which*CC + c)*MZ*MZ;
  float* LrB = Lr + (which*CC + c)*MZ*MZ;
  float* invB = invd + (which*CC + c)*MZ;
  __shared__ float As[MZ*MZ];   // col-major: As[col*128 + row]; input symmetric so straight copy is fine
  int tid = threadIdx.x;
  {
    float4* d4 = (float4*)As; const float4* s4 = (const float4*)Ain;
    for (int idx = tid; idx < MZ*MZ/4; idx += 256) d4[idx] = s4[idx];
  }
  __syncthreads();
  int i = tid & 127, kh = tid >> 7;
  for (int j = 0; j < MZ; j += 4) {
    // raw (post-prior-update) values
    float r0 = As[(j+0)*MZ + i], r1 = As[(j+1)*MZ + i], r2 = As[(j+2)*MZ + i], r3 = As[(j+3)*MZ + i];
    float a00 = As[j*MZ+j];
    float a10 = As[j*MZ+j+1], a20 = As[j*MZ+j+2], a30 = As[j*MZ+j+3];
    float a11 = As[(j+1)*MZ+j+1], a21 = As[(j+1)*MZ+j+2], a31 = As[(j+1)*MZ+j+3];
    float a22 = As[(j+2)*MZ+j+2], a32 = As[(j+2)*MZ+j+3];
    float a33 = As[(j+3)*MZ+j+3];
    float d0 = sqrtf(a00), id0 = 1.0f/d0;
    float l10 = a10*id0, l20 = a20*id0, l30 = a30*id0;
    float d1 = sqrtf(a11 - l10*l10), id1 = 1.0f/d1;
    float l21 = (a21 - l20*l10)*id1, l31 = (a31 - l30*l10)*id1;
    float d2 = sqrtf(a22 - l20*l20 - l21*l21), id2 = 1.0f/d2;
    float l32 = (a32 - l30*l20 - l31*l21)*id2;
    float d3 = sqrtf(a33 - l30*l30 - l31*l31 - l32*l32), id3 = 1.0f/d3;
    float c0 = r0*id0;
    float c1 = (r1 - c0*l10)*id1;
    float c2 = (r2 - c0*l20 - c1*l21)*id2;
    float c3 = (r3 - c0*l30 - c1*l31 - c2*l32)*id3;
    __syncthreads();      // raw reads complete before column writes
    if (kh == 0) {
      if (i >= j)   { As[(j+0)*MZ+i] = c0; LcB[(j+0)*MZ+i] = c0; LrB[i*MZ+j+0] = c0; if (i == j)   invB[i] = id0; }
      if (i >= j+1) { As[(j+1)*MZ+i] = c1; LcB[(j+1)*MZ+i] = c1; LrB[i*MZ+j+1] = c1; if (i == j+1) invB[i] = id1; }
      if (i >= j+2) { As[(j+2)*MZ+i] = c2; LcB[(j+2)*MZ+i] = c2; LrB[i*MZ+j+2] = c2; if (i == j+2) invB[i] = id2; }
      if (i >= j+3) { As[(j+3)*MZ+i] = c3; LcB[(j+3)*MZ+i] = c3; LrB[i*MZ+j+3] = c3; if (i == j+3) invB[i] = id3; }
    }
    __syncthreads();      // scaled columns visible
    for (int k = j+4+kh; k < MZ; k += 2) {   // rank-4 trailing update, split by kh parity
      float ck0 = As[(j+0)*MZ+k], ck1 = As[(j+1)*MZ+k], ck2 = As[(j+2)*MZ+k], ck3 = As[(j+3)*MZ+k];
      if (i >= k) As[k*MZ+i] -= c0*ck0 + c1*ck1 + c2*ck2 + c3*ck3;
    }
    __syncthreads();      // updates done before next block's raw reads
  }
}

// ylam[c] = Lb^{-1} Lambda_u[c] (forward substitution, one wave, shuffle broadcast)
__global__ __launch_bounds__(64) void k_ylam(const float* __restrict__ Lc, const float* __restrict__ LamU,
    float* __restrict__ ylam)
{
  int c = blockIdx.x, lane = threadIdx.x;
  const float* LB = Lc + (CC + c)*MZ*MZ;   // which=1 (Lb)
  __shared__ float Ls[MZ*MZ];
  {
    float4* d4 = (float4*)Ls; const float4* s4 = (const float4*)LB;
    for (int idx = lane; idx < MZ*MZ/4; idx += 64) d4[idx] = s4[idx];
  }
  __syncthreads();
  float b0 = LamU[c*MZ + lane], b1 = LamU[c*MZ + 64 + lane];
  float y0 = 0.0f, y1 = 0.0f;
  for (int j = 0; j < MZ; ++j) {
    float bj = (j < 64) ? __shfl(b0, j, 64) : __shfl(b1, j - 64, 64);
    float y = bj / Ls[j*MZ + j];
    if (j < 64) {
      if (lane == j) y0 = y;
      if (lane > j) b0 -= Ls[j*MZ + lane] * y;
      b1 -= Ls[j*MZ + 64 + lane] * y;
    } else {
      if (lane == j - 64) y1 = y;
      if (lane > j - 64) b1 -= Ls[j*MZ + 64 + lane] * y;
    }
  }
  ylam[c*MZ + lane] = y0; ylam[c*MZ + 64 + lane] = y1;
}

// Forward substitution L W = Kzxt for 128 RHS columns; accumulates sum(W^2) per column,
// and for which==1 also f_mean[t] = W[:,t] . ylam. Rank-4 over rows; RHS in LDS.
__global__ __launch_bounds__(128) void k_subst(const float* __restrict__ Kxz, const float* __restrict__ Lr,
    const float* __restrict__ invd, const float* __restrict__ ylam,
    float* __restrict__ ssq, float* __restrict__ fmean)
{
  int which = blockIdx.x & 1, c = blockIdx.x >> 1;
  const float* LrB = Lr + (which*CC + c)*MZ*MZ;
  const float* invB = invd + (which*CC + c)*MZ;
  const float* ylB = ylam + c*MZ;
  const float* KxzC = Kxz + c*TN*MZ;
  __shared__ float Bs[MZ*TN];   // Bs[row*128 + t]
  int t = threadIdx.x;
  {
    const float4* src = (const float4*)(KxzC + t*MZ);   // row t of Kxz = column t of Kzxt
    for (int i4 = 0; i4 < MZ/4; ++i4) {
      float4 v = src[i4];
      Bs[(4*i4+0)*TN + t] = v.x; Bs[(4*i4+1)*TN + t] = v.y;
      Bs[(4*i4+2)*TN + t] = v.z; Bs[(4*i4+3)*TN + t] = v.w;
    }
  }
  __syncthreads();
  float sq = 0, fm = 0;
  for (int j = 0; j < MZ; j += 4) {
    float b0v = Bs[(j+0)*TN + t], b1v = Bs[(j+1)*TN + t], b2v = Bs[(j+2)*TN + t], b3v = Bs[(j+3)*TN + t];
    float i0 = invB[j], i1 = invB[j+1], i2 = invB[j+2], i3 = invB[j+3];
    float L10 = LrB[(j+1)*MZ + j];
    float L20 = LrB[(j+2)*MZ + j], L21 = LrB[(j+2)*MZ + j+1];
    float L30 = LrB[(j+3)*MZ + j], L31 = LrB[(j+3)*MZ + j+1], L32 = LrB[(j+3)*MZ + j+2];
    float y0 = b0v * i0;
    float y1 = (b1v - L10*y0) * i1;
    float y2 = (b2v - L20*y0 - L21*y1) * i2;
    float y3 = (b3v - L30*y0 - L31*y1 - L32*y2) * i3;
    sq += y0*y0 + y1*y1 + y2*y2 + y3*y3;
    fm += y0*ylB[j] + y1*ylB[j+1] + y2*ylB[j+2] + y3*ylB[j+3];
    for (int i = j+4; i < MZ; ++i) {
      float4 lv = *(const float4*)(&LrB[i*MZ + j]);   // uniform -> scalar dwordx4
      Bs[i*TN + t] -= lv.x*y0 + lv.y*y1 + lv.z*y2 + lv.w*y3;
    }
  }
  ssq[(which*CC + c)*TN + t] = sq;
  if (which) fmean[c*TN + t] = fm;
}

// out[0][t][c] = f_mean ; out[1][t][c] = f_var.T = Kxx - sum(Am^2) + sum(Ab^2)
__global__ __launch_bounds__(256) void k_final(const float* __restrict__ fmean, const float* __restrict__ Kxxd,
    const float* __restrict__ ssq, float* __restrict__ out)
{
  int idx = blockIdx.x*256 + threadIdx.x;
  if (idx >= TN*CC) return;
  int t = idx / CC, c = idx % CC;
  out[idx] = fmean[c*TN + t];
  out[TN*CC + idx] = Kxxd[c*TN + t] - ssq[c*TN + t] + ssq[CC*TN + c*TN + t];
}

extern "C" void kernel_launch(void* const* d_in, const int* in_sizes, int n_in,
                              void* d_out, int out_size, void* d_ws, size_t ws_size,
                              hipStream_t stream) {
  (void)in_sizes; (void)n_in; (void)out_size; (void)ws_size;
  const float* X  = (const float*)d_in[0];
  const float* Y  = (const float*)d_in[1];
  const float* Z  = (const float*)d_in[2];
  const float* Xt = (const float*)d_in[3];
  const float* W1 = (const float*)d_in[4];
  const float* b1 = (const float*)d_in[5];
  const float* W2 = (const float*)d_in[6];
  const float* b2 = (const float*)d_in[7];
  const float* W3 = (const float*)d_in[8];
  float* ws  = (float*)d_ws;
  float* out = (float*)d_out;

  float* XS   = ws + OFF_XS;
  float* A1   = ws + OFF_A1;
  float* A2   = ws + OFF_A2;
  float* G1   = ws + OFF_G1;
  float* G2   = ws + OFF_G2;
  float* W2T  = ws + OFF_W2T;
  float* Base = ws + OFF_BASE;
  float* Kzx  = ws + OFF_KZX;
  float* Kzz  = ws + OFF_KZZ;
  float* Kxz  = ws + OFF_KXZ;
  float* Kxxd = ws + OFF_KXXD;
  float* Kzzj = ws + OFF_KZZJ;
  float* KzzB = ws + OFF_KZZB;
  float* LamU = ws + OFF_LAMU;
  float* Lc   = ws + OFF_LC;
  float* Lr   = ws + OFF_LR;
  float* invd = ws + OFF_INVD;
  float* ylam = ws + OFF_YLAM;
  float* ssq  = ws + OFF_SSQ;
  float* fmean= ws + OFF_FMEAN;

  k_w2t<<<128, 128, 0, stream>>>(W2, W2T);
  k_features<<<S_TOT, 128, 0, stream>>>(X, Z, Xt, W1, b1, W2, b2, W3, W2T, XS, A1, A2, G1, G2);
  k_base<<<dim3(16, 8, 3), 256, 0, stream>>>(XS, A1, A2, Base);
  k_gram<<<dim3(16, 8, 3*CC), 256, 0, stream>>>(G1, G2, Base, Kzx, Kzz, Kxz);
  k_kxxd<<<TN, 128, 0, stream>>>(XS, A1, A2, G1, G2, Kxxd);
  k_kzzb<<<dim3(8, 8, CC), 256, 0, stream>>>(Kzx, Kzz, Kzzj, KzzB);
  k_lambda<<<CC, 128, 0, stream>>>(Kzx, Y, LamU);
  k_chol<<<2*CC, 256, 0, stream>>>(Kzzj, KzzB, Lc, Lr, invd);
  k_ylam<<<CC, 64, 0, stream>>>(Lc, LamU, ylam);
  k_subst<<<2*CC, 128, 0, stream>>>(Kxz, Lr, invd, ylam, ssq, fmean);
  k_final<<<(TN*CC + 255)/256, 256, 0, stream>>>(fmean, Kxxd, ssq, out);
}

// Round 2
// 318.019 us; speedup vs baseline: 1.3233x; 1.3233x over previous
//
#include <hip/hip_runtime.h>

// NTK-SVGP forward: D=H=128, C=10, N=256, M=128, T=128, sigma2=1, delta=1
#define H 128
#define DD 128
#define CC 10
#define NX 256
#define MZ 128
#define TN 128
#define S_TOT 512   // samples: X[0..255], Z[256..383], X_test[384..511]
#define SCALE (1.0f/256.0f)   // 1/(delta*N)
#define JIT 1e-3f
#define INV_S2 1.0f

// ---------------- ws layout (float offsets) ----------------
#define OFF_XS    0u
#define OFF_A1    (OFF_XS   + S_TOT*DD)
#define OFF_A2    (OFF_A1   + S_TOT*H)
#define OFF_G1    (OFF_A2   + S_TOT*H)
#define OFF_G2    (OFF_G1   + S_TOT*CC*H)
#define OFF_W2T   (OFF_G2   + S_TOT*CC*H)
#define OFF_BASE  (OFF_W2T  + H*H)
#define BASE_ZX   0u
#define BASE_ZZ   (3u*MZ*NX)
#define BASE_TZ   (3u*MZ*NX + 3u*MZ*MZ)
#define OFF_KZX   (OFF_BASE + 3u*MZ*NX + 3u*MZ*MZ + 3u*TN*MZ)
#define OFF_KZZ   (OFF_KZX  + CC*MZ*NX)
#define OFF_KXZ   (OFF_KZZ  + CC*MZ*MZ)
#define OFF_KXXD  (OFF_KXZ  + CC*TN*MZ)
#define OFF_KZZJ  (OFF_KXXD + CC*TN)
#define OFF_KZZB  (OFF_KZZJ + CC*MZ*MZ)
#define OFF_LAMU  (OFF_KZZB + CC*MZ*MZ)
#define OFF_LPAN  (OFF_LAMU + CC*MZ)
#define OFF_INVD  (OFF_LPAN + 2u*CC*MZ*MZ)
#define OFF_YLAM  (OFF_INVD + 2u*CC*MZ)
#define OFF_SSQ   (OFF_YLAM + CC*MZ)
#define OFF_FMEAN (OFF_SSQ  + 2u*CC*TN)

__global__ __launch_bounds__(128) void k_w2t(const float* __restrict__ W2, float* __restrict__ W2T,
                                             float* __restrict__ LamU) {
  int k = blockIdx.x, h = threadIdx.x;
  W2T[k*H + h] = W2[h*H + k];
  if (k < CC) LamU[k*MZ + h] = 0.0f;   // zero for k_gram's atomic accumulation
}

// Per-sample forward + backprop features. One block per sample, 128 threads.
__global__ __launch_bounds__(128) void k_features(
    const float* __restrict__ X, const float* __restrict__ Z, const float* __restrict__ Xt,
    const float* __restrict__ W1, const float* __restrict__ b1,
    const float* __restrict__ W2, const float* __restrict__ b2,
    const float* __restrict__ W3, const float* __restrict__ W2T,
    float* __restrict__ XS, float* __restrict__ A1, float* __restrict__ A2,
    float* __restrict__ G1, float* __restrict__ G2)
{
  int s = blockIdx.x, h = threadIdx.x;
  const float* xin = (s < NX) ? X + s*DD : (s < NX+MZ ? Z + (s-NX)*DD : Xt + (s-NX-MZ)*DD);
  __shared__ float xs[DD], a1s[H], g2s[CC*H];
  float xv = xin[h];
  xs[h] = xv; XS[s*DD + h] = xv;
  __syncthreads();
  float acc = b1[h];
  #pragma unroll 4
  for (int d0 = 0; d0 < DD; ++d0) acc += xs[d0] * W1[d0*H + h];   // coalesced over h
  float a1 = tanhf(acc);
  a1s[h] = a1; A1[s*H + h] = a1;
  __syncthreads();
  acc = b2[h];
  #pragma unroll 4
  for (int d0 = 0; d0 < H; ++d0) acc += a1s[d0] * W2[d0*H + h];
  float a2 = tanhf(acc);
  A2[s*H + h] = a2;
  float t2 = 1.0f - a2*a2;
  #pragma unroll
  for (int c = 0; c < CC; ++c) {
    float g2 = W3[h*CC + c] * t2;
    g2s[c*H + h] = g2;
    G2[(s*CC + c)*H + h] = g2;
  }
  __syncthreads();
  float t1 = 1.0f - a1*a1;
  float accs[CC];
  #pragma unroll
  for (int c = 0; c < CC; ++c) accs[c] = 0.0f;
  for (int k = 0; k < H; ++k) {
    float w = W2T[k*H + h];        // coalesced over h
    #pragma unroll
    for (int c = 0; c < CC; ++c) accs[c] += w * g2s[c*H + k];   // broadcast
  }
  #pragma unroll
  for (int c = 0; c < CC; ++c) G1[(s*CC + c)*H + h] = t1 * accs[c];
}

// Class-independent base dot products: 1+x.x', 1+a1.a1', 1+a2.a2'
__global__ __launch_bounds__(256) void k_base(const float* __restrict__ XS,
    const float* __restrict__ A1, const float* __restrict__ A2, float* __restrict__ Base)
{
  int set = blockIdx.z;
  int colsN = (set == 0) ? NX : MZ;
  if ((int)blockIdx.x * 16 >= colsN) return;
  int rowOff = (set == 2) ? NX+MZ : NX;
  int colOff = (set == 0) ? 0 : NX;
  unsigned baseOff = (set == 0) ? BASE_ZX : (set == 1 ? BASE_ZZ : BASE_TZ);
  __shared__ float rx[16*132], r1[16*132], r2[16*132], cxs[16*132], c1s[16*132], c2s[16*132];
  int tid = threadIdx.x, m0 = blockIdx.y*16, n0 = blockIdx.x*16;
  for (int idx = tid; idx < 16*128; idx += 256) {
    int r = idx >> 7, hh = idx & 127;
    int sr = rowOff + m0 + r, sc = colOff + n0 + r;
    rx [r*132+hh] = XS[sr*DD+hh]; r1[r*132+hh] = A1[sr*H+hh]; r2[r*132+hh] = A2[sr*H+hh];
    cxs[r*132+hh] = XS[sc*DD+hh]; c1s[r*132+hh] = A1[sc*H+hh]; c2s[r*132+hh] = A2[sc*H+hh];
  }
  __syncthreads();
  int ty = tid >> 4, tx = tid & 15;
  const float4* pa = (const float4*)(rx  + ty*132);
  const float4* pb = (const float4*)(cxs + tx*132);
  const float4* pc = (const float4*)(r1  + ty*132);
  const float4* pd = (const float4*)(c1s + tx*132);
  const float4* pe = (const float4*)(r2  + ty*132);
  const float4* pf = (const float4*)(c2s + tx*132);
  float d0 = 0, d1 = 0, d2 = 0;
  #pragma unroll 8
  for (int q = 0; q < 32; ++q) {
    float4 a = pa[q], b = pb[q]; d0 += a.x*b.x + a.y*b.y + a.z*b.z + a.w*b.w;
    float4 c = pc[q], d = pd[q]; d1 += c.x*d.x + c.y*d.y + c.z*d.z + c.w*d.w;
    float4 e = pe[q], f = pf[q]; d2 += e.x*f.x + e.y*f.y + e.z*f.z + e.w*f.w;
  }
  int m = m0 + ty, n = n0 + tx;
  float* Bp = Base + baseOff;
  int area = 128 * colsN;
  Bp[0*area + m*colsN + n] = 1.0f + d0;
  Bp[1*area + m*colsN + n] = 1.0f + d1;
  Bp[2*area + m*colsN + n] = 1.0f + d2;
}

// Per-class NTK gram: K = SCALE*(B0*(g1.g1') + B1*(g2.g2') + B2)
// set==0 additionally folds LamU[c][m] += sum_n Kzx[m][n]*Y[n][c] via shuffles+atomics.
__global__ __launch_bounds__(256) void k_gram(const float* __restrict__ G1, const float* __restrict__ G2,
    const float* __restrict__ Base, const float* __restrict__ Y,
    float* __restrict__ Kzx, float* __restrict__ Kzz, float* __restrict__ Kxz,
    float* __restrict__ LamU)
{
  int z = blockIdx.z, set = z / CC, c = z % CC;
  int colsN = (set == 0) ? NX : MZ;
  if ((int)blockIdx.x * 16 >= colsN) return;
  int rowOff = (set == 2) ? NX+MZ : NX;
  int colOff = (set == 0) ? 0 : NX;
  unsigned baseOff = (set == 0) ? BASE_ZX : (set == 1 ? BASE_ZZ : BASE_TZ);
  float* outp = (set == 0) ? Kzx + c*MZ*NX : (set == 1 ? Kzz + c*MZ*MZ : Kxz + c*TN*MZ);
  __shared__ float g1r[16*132], g2r[16*132], g1c[16*132], g2c[16*132];
  int tid = threadIdx.x, m0 = blockIdx.y*16, n0 = blockIdx.x*16;
  for (int idx = tid; idx < 2048; idx += 256) {
    int r = idx >> 7, hh = idx & 127;
    int sr = rowOff + m0 + r, sc = colOff + n0 + r;
    g1r[r*132+hh] = G1[(sr*CC + c)*H + hh]; g2r[r*132+hh] = G2[(sr*CC + c)*H + hh];
    g1c[r*132+hh] = G1[(sc*CC + c)*H + hh]; g2c[r*132+hh] = G2[(sc*CC + c)*H + hh];
  }
  __syncthreads();
  int ty = tid >> 4, tx = tid & 15;
  const float4* p1 = (const float4*)(g1r + ty*132);
  const float4* p2 = (const float4*)(g1c + tx*132);
  const float4* p3 = (const float4*)(g2r + ty*132);
  const float4* p4 = (const float4*)(g2c + tx*132);
  float dg1 = 0, dg2 = 0;
  #pragma unroll 8
  for (int q = 0; q < 32; ++q) {
    float4 a = p1[q], b = p2[q]; dg1 += a.x*b.x + a.y*b.y + a.z*b.z + a.w*b.w;
    float4 e = p3[q], f = p4[q]; dg2 += e.x*f.x + e.y*f.y + e.z*f.z + e.w*f.w;
  }
  int m = m0 + ty, n = n0 + tx;
  const float* Bp = Base + baseOff;
  int area = 128 * colsN;
  float b0 = Bp[m*colsN + n], b1v = Bp[area + m*colsN + n], b2v = Bp[2*area + m*colsN + n];
  float val = SCALE * (b0*dg1 + b1v*dg2 + b2v);
  outp[m*colsN + n] = val;
  if (set == 0) {
    float lam = val * Y[n*CC + c] * INV_S2;
    lam += __shfl_xor(lam, 1, 64); lam += __shfl_xor(lam, 2, 64);
    lam += __shfl_xor(lam, 4, 64); lam += __shfl_xor(lam, 8, 64);
    if (tx == 0) atomicAdd(&LamU[c*MZ + m], lam);
  }
}

__device__ __forceinline__ float blockReduce128(float v, float* red, int h) {
  #pragma unroll
  for (int off = 32; off > 0; off >>= 1) v += __shfl_down(v, off, 64);
  if ((h & 63) == 0) red[h >> 6] = v;
  __syncthreads();
  float r = red[0] + red[1];
  __syncthreads();
  return r;
}

// Kxx_diag[c][t]; one block per test sample.
__global__ __launch_bounds__(128) void k_kxxd(const float* __restrict__ XS, const float* __restrict__ A1,
    const float* __restrict__ A2, const float* __restrict__ G1, const float* __restrict__ G2,
    float* __restrict__ Kxxd)
{
  int t = blockIdx.x, h = threadIdx.x, s = NX + MZ + t;
  __shared__ float red[2];
  float xv = XS[s*DD+h], a1v = A1[s*H+h], a2v = A2[s*H+h];
  float nx  = blockReduce128(xv*xv,  red, h);
  float na1 = blockReduce128(a1v*a1v, red, h);
  float na2 = blockReduce128(a2v*a2v, red, h);
  for (int c = 0; c < CC; ++c) {
    float g1 = G1[(s*CC+c)*H+h], g2 = G2[(s*CC+c)*H+h];
    float n1 = blockReduce128(g1*g1, red, h);
    float n2 = blockReduce128(g2*g2, red, h);
    if (h == 0) Kxxd[c*TN + t] = SCALE * ((1.0f+nx)*n1 + (1.0f+na1)*n2 + (1.0f+na2));
  }
}

// KzzB = Kzz + Kzx Kzx^T / sigma2 + 2*JIT*I ; Kzzj = Kzz + JIT*I
__global__ __launch_bounds__(256) void k_kzzb(const float* __restrict__ Kzx, const float* __restrict__ Kzz,
    float* __restrict__ Kzzj, float* __restrict__ KzzB)
{
  int c = blockIdx.z, m0 = blockIdx.y*16, k0 = blockIdx.x*16;
  int tid = threadIdx.x, ty = tid >> 4, tx = tid & 15;
  __shared__ float Am[16*17], Ak[16*17];
  const float* Kc = Kzx + c*MZ*NX;
  float acc = 0;
  for (int nc = 0; nc < NX; nc += 16) {
    Am[ty*17+tx] = Kc[(m0+ty)*NX + nc + tx];
    Ak[ty*17+tx] = Kc[(k0+ty)*NX + nc + tx];
    __syncthreads();
    #pragma unroll
    for (int p = 0; p < 16; ++p) acc += Am[ty*17+p] * Ak[tx*17+p];
    __syncthreads();
  }
  int m = m0+ty, k = k0+tx, idx = c*MZ*MZ + m*MZ + k;
  float kzz = Kzz[idx];
  float dia = (m == k) ? 1.0f : 0.0f;
  Kzzj[idx] = kzz + dia*JIT;
  KzzB[idx] = kzz + acc*INV_S2 + dia*2.0f*JIT;
}

// Blocked (rank-4) Cholesky, in-LDS, column-major. Writes Lpan (panel float4 layout) + invd.
// Lpan[(which*CC+c)] as float4: [jb][i] = (L[i][4jb],L[i][4jb+1],L[i][4jb+2],L[i][4jb+3])
__global__ __launch_bounds__(256) void k_chol(const float* __restrict__ Kzzj, const float* __restrict__ KzzB,
    float* __restrict__ Lpan, float* __restrict__ invd)
{
  int which = blockIdx.x & 1, c = blockIdx.x >> 1;
  const float* Ain = (which ? KzzB : Kzzj) + c*MZ*MZ;
  float4* LpB = (float4*)(Lpan + (size_t)(which*CC + c)*MZ*MZ);
  float* invB = invd + (which*CC + c)*MZ;
  __shared__ float As[MZ*MZ];   // col-major; input symmetric so straight copy is fine
  int tid = threadIdx.x;
  {
    float4* d4 = (float4*)As; const float4* s4 = (const float4*)Ain;
    for (int idx = tid; idx < MZ*MZ/4; idx += 256) d4[idx] = s4[idx];
  }
  __syncthreads();
  int i = tid & 127, kh = tid >> 7;
  for (int j = 0; j < MZ; j += 4) {
    float r0 = As[(j+0)*MZ + i], r1 = As[(j+1)*MZ + i], r2 = As[(j+2)*MZ + i], r3 = As[(j+3)*MZ + i];
    float a00 = As[j*MZ+j];
    float a10 = As[j*MZ+j+1], a20 = As[j*MZ+j+2], a30 = As[j*MZ+j+3];
    float a11 = As[(j+1)*MZ+j+1], a21 = As[(j+1)*MZ+j+2], a31 = As[(j+1)*MZ+j+3];
    float a22 = As[(j+2)*MZ+j+2], a32 = As[(j+2)*MZ+j+3];
    float a33 = As[(j+3)*MZ+j+3];
    float d0 = sqrtf(a00), id0 = 1.0f/d0;
    float l10 = a10*id0, l20 = a20*id0, l30 = a30*id0;
    float d1 = sqrtf(a11 - l10*l10), id1 = 1.0f/d1;
    float l21 = (a21 - l20*l10)*id1, l31 = (a31 - l30*l10)*id1;
    float d2 = sqrtf(a22 - l20*l20 - l21*l21), id2 = 1.0f/d2;
    float l32 = (a32 - l30*l20 - l31*l21)*id2;
    float d3 = sqrtf(a33 - l30*l30 - l31*l31 - l32*l32), id3 = 1.0f/d3;
    float c0 = r0*id0;
    float c1 = (r1 - c0*l10)*id1;
    float c2 = (r2 - c0*l20 - c1*l21)*id2;
    float c3 = (r3 - c0*l30 - c1*l31 - c2*l32)*id3;
    __syncthreads();      // raw reads complete before column writes
    if (kh == 0) {
      LpB[(j>>2)*MZ + i] = make_float4(c0, c1, c2, c3);   // panel row (garbage above diag, unused)
      if (i >= j)   { As[(j+0)*MZ+i] = c0; if (i == j)   invB[i] = id0; }
      if (i >= j+1) { As[(j+1)*MZ+i] = c1; if (i == j+1) invB[i] = id1; }
      if (i >= j+2) { As[(j+2)*MZ+i] = c2; if (i == j+2) invB[i] = id2; }
      if (i >= j+3) { As[(j+3)*MZ+i] = c3; if (i == j+3) invB[i] = id3; }
    }
    __syncthreads();      // scaled columns visible
    for (int k = j+4+kh; k < MZ; k += 2) {   // rank-4 trailing update, split by kh parity
      float ck0 = As[(j+0)*MZ+k], ck1 = As[(j+1)*MZ+k], ck2 = As[(j+2)*MZ+k], ck3 = As[(j+3)*MZ+k];
      if (i >= k) As[k*MZ+i] -= c0*ck0 + c1*ck1 + c2*ck2 + c3*ck3;
    }
    __syncthreads();      // updates done before next block's raw reads
  }
}

// ylam[c] = Lb^{-1} Lambda_u[c] (forward substitution, one wave, reads Lpan which=1)
__global__ __launch_bounds__(64) void k_ylam(const float* __restrict__ Lpan, const float* __restrict__ invd,
    const float* __restrict__ LamU, float* __restrict__ ylam)
{
  int c = blockIdx.x, lane = threadIdx.x;
  const float4* LB = (const float4*)(Lpan + (size_t)(CC + c)*MZ*MZ);
  const float* invB = invd + (CC + c)*MZ;
  __shared__ float4 Ls[MZ*MZ/4];   // exactly 64 KiB
  for (int idx = lane; idx < MZ*MZ/4; idx += 64) Ls[idx] = LB[idx];
  const float* Lf = (const float*)Ls;
  float iv0 = invB[lane], iv1 = invB[64+lane];
  float b0 = LamU[c*MZ + lane], b1 = LamU[c*MZ + 64 + lane];
  float y0 = 0.0f, y1 = 0.0f;
  for (int j = 0; j < MZ; ++j) {
    int jb = j >> 2, q = j & 3;
    float bj = (j < 64) ? __shfl(b0, j, 64) : __shfl(b1, j - 64, 64);
    float iv = (j < 64) ? __shfl(iv0, j, 64) : __shfl(iv1, j - 64, 64);
    float y = bj * iv;
    float l0 = Lf[(jb*MZ + lane)*4 + q];        // L[lane][j] (valid for lane>j)
    float l1 = Lf[(jb*MZ + 64 + lane)*4 + q];   // L[64+lane][j]
    if (j < 64) {
      if (lane == j) y0 = y;
      if (lane > j) b0 -= l0 * y;
      b1 -= l1 * y;
    } else {
      if (lane == j - 64) y1 = y;
      if (lane > j - 64) b1 -= l1 * y;
    }
  }
  ylam[c*MZ + lane] = y0; ylam[c*MZ + 64 + lane] = y1;
}

// Forward substitution L W = Kzxt, 64 RHS columns per block, single wave, no barriers.
// grid 40 = (c, which, colhalf). Accumulates sum(W^2) and (which==1) f_mean = W . ylam.
__global__ __launch_bounds__(64) void k_subst(const float* __restrict__ Kxz,
    const float* __restrict__ Lpan, const float* __restrict__ invd,
    const float* __restrict__ ylam, float* __restrict__ ssq, float* __restrict__ fmean)
{
  int half  = blockIdx.x & 1;
  int which = (blockIdx.x >> 1) & 1;
  int c     = blockIdx.x >> 2;
  const float4* LpB = (const float4*)(Lpan + (size_t)(which*CC + c)*MZ*MZ);
  const float*  invB = invd + (which*CC + c)*MZ;
  const float*  ylB  = ylam + c*MZ;
  int lane = threadIdx.x;
  int tt = half*64 + lane;
  __shared__ float  Bs[MZ*64];     // 32 KiB, column per lane, stride 64 (conflict-free)
  __shared__ float4 Pp[2][MZ];     // double-buffered L panel
  __shared__ float  invS[MZ], ylS[MZ];
  invS[lane] = invB[lane]; invS[64+lane] = invB[64+lane];
  ylS[lane]  = ylB[lane];  ylS[64+lane]  = ylB[64+lane];
  // load column tt of Kzxt = row tt of Kxz[c]
  const float4* src = (const float4*)(Kxz + (size_t)c*TN*MZ + (size_t)tt*MZ);
  #pragma unroll 4
  for (int i4 = 0; i4 < MZ/4; ++i4) {
    float4 v = src[i4];
    Bs[(4*i4+0)*64 + lane] = v.x;
    Bs[(4*i4+1)*64 + lane] = v.y;
    Bs[(4*i4+2)*64 + lane] = v.z;
    Bs[(4*i4+3)*64 + lane] = v.w;
  }
  Pp[0][lane]    = LpB[lane];
  Pp[0][64+lane] = LpB[64+lane];
  int cur = 0;
  float sq = 0.0f, fm = 0.0f;
  for (int jb = 0; jb < MZ/4; ++jb) {
    int j = jb*4;
    float4 pf0 = {0,0,0,0}, pf1 = {0,0,0,0};
    if (jb < MZ/4 - 1) { pf0 = LpB[(jb+1)*MZ + lane]; pf1 = LpB[(jb+1)*MZ + 64 + lane]; }
    float4 q1 = Pp[cur][j+1], q2 = Pp[cur][j+2], q3 = Pp[cur][j+3];
    float i0 = invS[j], i1 = invS[j+1], i2 = invS[j+2], i3 = invS[j+3];
    float b0 = Bs[(j+0)*64+lane], b1 = Bs[(j+1)*64+lane], b2 = Bs[(j+2)*64+lane], b3 = Bs[(j+3)*64+lane];
    float y0 = b0*i0;
    float y1 = (b1 - q1.x*y0)*i1;
    float y2 = (b2 - q2.x*y0 - q2.y*y1)*i2;
    float y3 = (b3 - q3.x*y0 - q3.y*y1 - q3.z*y2)*i3;
    sq += y0*y0 + y1*y1 + y2*y2 + y3*y3;
    fm += y0*ylS[j] + y1*ylS[j+1] + y2*ylS[j+2] + y3*ylS[j+3];
    for (int i = j+4; i < MZ; ++i) {
      float4 lv = Pp[cur][i];                         // broadcast b128
      Bs[i*64+lane] -= lv.x*y0 + lv.y*y1 + lv.z*y2 + lv.w*y3;
    }
    if (jb < MZ/4 - 1) { Pp[cur^1][lane] = pf0; Pp[cur^1][64+lane] = pf1; }
    cur ^= 1;
  }
  ssq[(which*CC + c)*TN + tt] = sq;
  if (which) fmean[c*TN + tt] = fm;
}

// out[0][t][c] = f_mean ; out[1][t][c] = f_var.T = Kxx - sum(Am^2) + sum(Ab^2)
__global__ __launch_bounds__(256) void k_final(const float* __restrict__ fmean, const float* __restrict__ Kxxd,
    const float* __restrict__ ssq, float* __restrict__ out)
{
  int idx = blockIdx.x*256 + threadIdx.x;
  if (idx >= TN*CC) return;
  int t = idx / CC, c = idx % CC;
  out[idx] = fmean[c*TN + t];
  out[TN*CC + idx] = Kxxd[c*TN + t] - ssq[c*TN + t] + ssq[CC*TN + c*TN + t];
}

extern "C" void kernel_launch(void* const* d_in, const int* in_sizes, int n_in,
                              void* d_out, int out_size, void* d_ws, size_t ws_size,
                              hipStream_t stream) {
  (void)in_sizes; (void)n_in; (void)out_size; (void)ws_size;
  const float* X  = (const float*)d_in[0];
  const float* Y  = (const float*)d_in[1];
  const float* Z  = (const float*)d_in[2];
  const float* Xt = (const float*)d_in[3];
  const float* W1 = (const float*)d_in[4];
  const float* b1 = (const float*)d_in[5];
  const float* W2 = (const float*)d_in[6];
  const float* b2 = (const float*)d_in[7];
  const float* W3 = (const float*)d_in[8];
  float* ws  = (float*)d_ws;
  float* out = (float*)d_out;

  float* XS   = ws + OFF_XS;
  float* A1   = ws + OFF_A1;
  float* A2   = ws + OFF_A2;
  float* G1   = ws + OFF_G1;
  float* G2   = ws + OFF_G2;
  float* W2T  = ws + OFF_W2T;
  float* Base = ws + OFF_BASE;
  float* Kzx  = ws + OFF_KZX;
  float* Kzz  = ws + OFF_KZZ;
  float* Kxz  = ws + OFF_KXZ;
  float* Kxxd = ws + OFF_KXXD;
  float* Kzzj = ws + OFF_KZZJ;
  float* KzzB = ws + OFF_KZZB;
  float* LamU = ws + OFF_LAMU;
  float* Lpan = ws + OFF_LPAN;
  float* invd = ws + OFF_INVD;
  float* ylam = ws + OFF_YLAM;
  float* ssq  = ws + OFF_SSQ;
  float* fmean= ws + OFF_FMEAN;

  k_w2t<<<128, 128, 0, stream>>>(W2, W2T, LamU);
  k_features<<<S_TOT, 128, 0, stream>>>(X, Z, Xt, W1, b1, W2, b2, W3, W2T, XS, A1, A2, G1, G2);
  k_base<<<dim3(16, 8, 3), 256, 0, stream>>>(XS, A1, A2, Base);
  k_gram<<<dim3(16, 8, 3*CC), 256, 0, stream>>>(G1, G2, Base, Y, Kzx, Kzz, Kxz, LamU);
  k_kxxd<<<TN, 128, 0, stream>>>(XS, A1, A2, G1, G2, Kxxd);
  k_kzzb<<<dim3(8, 8, CC), 256, 0, stream>>>(Kzx, Kzz, Kzzj, KzzB);
  k_chol<<<2*CC, 256, 0, stream>>>(Kzzj, KzzB, Lpan, invd);
  k_ylam<<<CC, 64, 0, stream>>>(Lpan, invd, LamU, ylam);
  k_subst<<<4*CC, 64, 0, stream>>>(Kxz, Lpan, invd, ylam, ssq, fmean);
  k_final<<<(TN*CC + 255)/256, 256, 0, stream>>>(fmean, Kxxd, ssq, out);
}

// Round 3
// 288.101 us; speedup vs baseline: 1.4607x; 1.1038x over previous
//
#include <hip/hip_runtime.h>

// NTK-SVGP forward: D=H=128, C=10, N=256, M=128, T=128, sigma2=1, delta=1
#define H 128
#define DD 128
#define CC 10
#define NX 256
#define MZ 128
#define TN 128
#define S_TOT 512   // samples: X[0..255], Z[256..383], X_test[384..511]
#define SCALE (1.0f/256.0f)   // 1/(delta*N)
#define JIT 1e-3f
#define INV_S2 1.0f

// ---------------- ws layout (float offsets) ----------------
#define OFF_XS    0u
#define OFF_A1    (OFF_XS   + S_TOT*DD)
#define OFF_A2    (OFF_A1   + S_TOT*H)
#define OFF_G1    (OFF_A2   + S_TOT*H)
#define OFF_G2    (OFF_G1   + S_TOT*CC*H)
#define OFF_W2T   (OFF_G2   + S_TOT*CC*H)
#define OFF_BASE  (OFF_W2T  + H*H)
#define BASE_ZX   0u
#define BASE_ZZ   (3u*MZ*NX)
#define BASE_TZ   (3u*MZ*NX + 3u*MZ*MZ)
#define OFF_KZX   (OFF_BASE + 3u*MZ*NX + 3u*MZ*MZ + 3u*TN*MZ)
#define OFF_KZZ   (OFF_KZX  + CC*MZ*NX)
#define OFF_KXZ   (OFF_KZZ  + CC*MZ*MZ)
#define OFF_KXXD  (OFF_KXZ  + CC*TN*MZ)
#define OFF_KZZJ  (OFF_KXXD + CC*TN)
#define OFF_KZZB  (OFF_KZZJ + CC*MZ*MZ)
#define OFF_LAMU  (OFF_KZZB + CC*MZ*MZ)
#define OFF_LPAN  (OFF_LAMU + CC*MZ)
#define OFF_INVD  (OFF_LPAN + 2u*CC*MZ*MZ)
#define OFF_YLAM  (OFF_INVD + 2u*CC*MZ)
#define OFF_SSQ   (OFF_YLAM + CC*MZ)
#define OFF_FMEAN (OFF_SSQ  + 2u*CC*TN)

__global__ __launch_bounds__(128) void k_w2t(const float* __restrict__ W2, float* __restrict__ W2T,
                                             float* __restrict__ LamU) {
  int k = blockIdx.x, h = threadIdx.x;
  W2T[k*H + h] = W2[h*H + k];
  if (k < CC) LamU[k*MZ + h] = 0.0f;   // zero for k_gram's atomic accumulation
}

// Per-sample forward + backprop features. One block per sample, 128 threads.
__global__ __launch_bounds__(128) void k_features(
    const float* __restrict__ X, const float* __restrict__ Z, const float* __restrict__ Xt,
    const float* __restrict__ W1, const float* __restrict__ b1,
    const float* __restrict__ W2, const float* __restrict__ b2,
    const float* __restrict__ W3, const float* __restrict__ W2T,
    float* __restrict__ XS, float* __restrict__ A1, float* __restrict__ A2,
    float* __restrict__ G1, float* __restrict__ G2)
{
  int s = blockIdx.x, h = threadIdx.x;
  const float* xin = (s < NX) ? X + s*DD : (s < NX+MZ ? Z + (s-NX)*DD : Xt + (s-NX-MZ)*DD);
  __shared__ float xs[DD], a1s[H], g2s[CC*H];
  float xv = xin[h];
  xs[h] = xv; XS[s*DD + h] = xv;
  __syncthreads();
  float acc = b1[h];
  #pragma unroll 4
  for (int d0 = 0; d0 < DD; ++d0) acc += xs[d0] * W1[d0*H + h];   // coalesced over h
  float a1 = tanhf(acc);
  a1s[h] = a1; A1[s*H + h] = a1;
  __syncthreads();
  acc = b2[h];
  #pragma unroll 4
  for (int d0 = 0; d0 < H; ++d0) acc += a1s[d0] * W2[d0*H + h];
  float a2 = tanhf(acc);
  A2[s*H + h] = a2;
  float t2 = 1.0f - a2*a2;
  #pragma unroll
  for (int c = 0; c < CC; ++c) {
    float g2 = W3[h*CC + c] * t2;
    g2s[c*H + h] = g2;
    G2[(s*CC + c)*H + h] = g2;
  }
  __syncthreads();
  float t1 = 1.0f - a1*a1;
  float accs[CC];
  #pragma unroll
  for (int c = 0; c < CC; ++c) accs[c] = 0.0f;
  for (int k = 0; k < H; ++k) {
    float w = W2T[k*H + h];        // coalesced over h
    #pragma unroll
    for (int c = 0; c < CC; ++c) accs[c] += w * g2s[c*H + k];   // broadcast
  }
  #pragma unroll
  for (int c = 0; c < CC; ++c) G1[(s*CC + c)*H + h] = t1 * accs[c];
}

// Class-independent base dot products: 1+x.x', 1+a1.a1', 1+a2.a2'
__global__ __launch_bounds__(256) void k_base(const float* __restrict__ XS,
    const float* __restrict__ A1, const float* __restrict__ A2, float* __restrict__ Base)
{
  int set = blockIdx.z;
  int colsN = (set == 0) ? NX : MZ;
  if ((int)blockIdx.x * 16 >= colsN) return;
  int rowOff = (set == 2) ? NX+MZ : NX;
  int colOff = (set == 0) ? 0 : NX;
  unsigned baseOff = (set == 0) ? BASE_ZX : (set == 1 ? BASE_ZZ : BASE_TZ);
  __shared__ float rx[16*132], r1[16*132], r2[16*132], cxs[16*132], c1s[16*132], c2s[16*132];
  int tid = threadIdx.x, m0 = blockIdx.y*16, n0 = blockIdx.x*16;
  for (int idx = tid; idx < 16*128; idx += 256) {
    int r = idx >> 7, hh = idx & 127;
    int sr = rowOff + m0 + r, sc = colOff + n0 + r;
    rx [r*132+hh] = XS[sr*DD+hh]; r1[r*132+hh] = A1[sr*H+hh]; r2[r*132+hh] = A2[sr*H+hh];
    cxs[r*132+hh] = XS[sc*DD+hh]; c1s[r*132+hh] = A1[sc*H+hh]; c2s[r*132+hh] = A2[sc*H+hh];
  }
  __syncthreads();
  int ty = tid >> 4, tx = tid & 15;
  const float4* pa = (const float4*)(rx  + ty*132);
  const float4* pb = (const float4*)(cxs + tx*132);
  const float4* pc = (const float4*)(r1  + ty*132);
  const float4* pd = (const float4*)(c1s + tx*132);
  const float4* pe = (const float4*)(r2  + ty*132);
  const float4* pf = (const float4*)(c2s + tx*132);
  float d0 = 0, d1 = 0, d2 = 0;
  #pragma unroll 8
  for (int q = 0; q < 32; ++q) {
    float4 a = pa[q], b = pb[q]; d0 += a.x*b.x + a.y*b.y + a.z*b.z + a.w*b.w;
    float4 c = pc[q], d = pd[q]; d1 += c.x*d.x + c.y*d.y + c.z*d.z + c.w*d.w;
    float4 e = pe[q], f = pf[q]; d2 += e.x*f.x + e.y*f.y + e.z*f.z + e.w*f.w;
  }
  int m = m0 + ty, n = n0 + tx;
  float* Bp = Base + baseOff;
  int area = 128 * colsN;
  Bp[0*area + m*colsN + n] = 1.0f + d0;
  Bp[1*area + m*colsN + n] = 1.0f + d1;
  Bp[2*area + m*colsN + n] = 1.0f + d2;
}

// Per-class NTK gram: K = SCALE*(B0*(g1.g1') + B1*(g2.g2') + B2)
// set==0 additionally folds LamU[c][m] += sum_n Kzx[m][n]*Y[n][c] via shuffles+atomics.
__global__ __launch_bounds__(256) void k_gram(const float* __restrict__ G1, const float* __restrict__ G2,
    const float* __restrict__ Base, const float* __restrict__ Y,
    float* __restrict__ Kzx, float* __restrict__ Kzz, float* __restrict__ Kxz,
    float* __restrict__ LamU)
{
  int z = blockIdx.z, set = z / CC, c = z % CC;
  int colsN = (set == 0) ? NX : MZ;
  if ((int)blockIdx.x * 16 >= colsN) return;
  int rowOff = (set == 2) ? NX+MZ : NX;
  int colOff = (set == 0) ? 0 : NX;
  unsigned baseOff = (set == 0) ? BASE_ZX : (set == 1 ? BASE_ZZ : BASE_TZ);
  float* outp = (set == 0) ? Kzx + c*MZ*NX : (set == 1 ? Kzz + c*MZ*MZ : Kxz + c*TN*MZ);
  __shared__ float g1r[16*132], g2r[16*132], g1c[16*132], g2c[16*132];
  int tid = threadIdx.x, m0 = blockIdx.y*16, n0 = blockIdx.x*16;
  for (int idx = tid; idx < 2048; idx += 256) {
    int r = idx >> 7, hh = idx & 127;
    int sr = rowOff + m0 + r, sc = colOff + n0 + r;
    g1r[r*132+hh] = G1[(sr*CC + c)*H + hh]; g2r[r*132+hh] = G2[(sr*CC + c)*H + hh];
    g1c[r*132+hh] = G1[(sc*CC + c)*H + hh]; g2c[r*132+hh] = G2[(sc*CC + c)*H + hh];
  }
  __syncthreads();
  int ty = tid >> 4, tx = tid & 15;
  const float4* p1 = (const float4*)(g1r + ty*132);
  const float4* p2 = (const float4*)(g1c + tx*132);
  const float4* p3 = (const float4*)(g2r + ty*132);
  const float4* p4 = (const float4*)(g2c + tx*132);
  float dg1 = 0, dg2 = 0;
  #pragma unroll 8
  for (int q = 0; q < 32; ++q) {
    float4 a = p1[q], b = p2[q]; dg1 += a.x*b.x + a.y*b.y + a.z*b.z + a.w*b.w;
    float4 e = p3[q], f = p4[q]; dg2 += e.x*f.x + e.y*f.y + e.z*f.z + e.w*f.w;
  }
  int m = m0 + ty, n = n0 + tx;
  const float* Bp = Base + baseOff;
  int area = 128 * colsN;
  float b0 = Bp[m*colsN + n], b1v = Bp[area + m*colsN + n], b2v = Bp[2*area + m*colsN + n];
  float val = SCALE * (b0*dg1 + b1v*dg2 + b2v);
  outp[m*colsN + n] = val;
  if (set == 0) {
    float lam = val * Y[n*CC + c] * INV_S2;
    lam += __shfl_xor(lam, 1, 64); lam += __shfl_xor(lam, 2, 64);
    lam += __shfl_xor(lam, 4, 64); lam += __shfl_xor(lam, 8, 64);
    if (tx == 0) atomicAdd(&LamU[c*MZ + m], lam);
  }
}

__device__ __forceinline__ float blockReduce128(float v, float* red, int h) {
  #pragma unroll
  for (int off = 32; off > 0; off >>= 1) v += __shfl_down(v, off, 64);
  if ((h & 63) == 0) red[h >> 6] = v;
  __syncthreads();
  float r = red[0] + red[1];
  __syncthreads();
  return r;
}

// Kxx_diag[c][t]; one block per test sample.
__global__ __launch_bounds__(128) void k_kxxd(const float* __restrict__ XS, const float* __restrict__ A1,
    const float* __restrict__ A2, const float* __restrict__ G1, const float* __restrict__ G2,
    float* __restrict__ Kxxd)
{
  int t = blockIdx.x, h = threadIdx.x, s = NX + MZ + t;
  __shared__ float red[2];
  float xv = XS[s*DD+h], a1v = A1[s*H+h], a2v = A2[s*H+h];
  float nx  = blockReduce128(xv*xv,  red, h);
  float na1 = blockReduce128(a1v*a1v, red, h);
  float na2 = blockReduce128(a2v*a2v, red, h);
  for (int c = 0; c < CC; ++c) {
    float g1 = G1[(s*CC+c)*H+h], g2 = G2[(s*CC+c)*H+h];
    float n1 = blockReduce128(g1*g1, red, h);
    float n2 = blockReduce128(g2*g2, red, h);
    if (h == 0) Kxxd[c*TN + t] = SCALE * ((1.0f+nx)*n1 + (1.0f+na1)*n2 + (1.0f+na2));
  }
}

// KzzB = Kzz + Kzx Kzx^T / sigma2 + 2*JIT*I ; Kzzj = Kzz + JIT*I
__global__ __launch_bounds__(256) void k_kzzb(const float* __restrict__ Kzx, const float* __restrict__ Kzz,
    float* __restrict__ Kzzj, float* __restrict__ KzzB)
{
  int c = blockIdx.z, m0 = blockIdx.y*16, k0 = blockIdx.x*16;
  int tid = threadIdx.x, ty = tid >> 4, tx = tid & 15;
  __shared__ float Am[16*17], Ak[16*17];
  const float* Kc = Kzx + c*MZ*NX;
  float acc = 0;
  for (int nc = 0; nc < NX; nc += 16) {
    Am[ty*17+tx] = Kc[(m0+ty)*NX + nc + tx];
    Ak[ty*17+tx] = Kc[(k0+ty)*NX + nc + tx];
    __syncthreads();
    #pragma unroll
    for (int p = 0; p < 16; ++p) acc += Am[ty*17+p] * Ak[tx*17+p];
    __syncthreads();
  }
  int m = m0+ty, k = k0+tx, idx = c*MZ*MZ + m*MZ + k;
  float kzz = Kzz[idx];
  float dia = (m == k) ? 1.0f : 0.0f;
  Kzzj[idx] = kzz + dia*JIT;
  KzzB[idx] = kzz + acc*INV_S2 + dia*2.0f*JIT;
}

// Blocked (rank-4) Cholesky, in-LDS, col-major. Alias-free trailing update via separate
// pan[] array + 8-wide batched rmw. Folds the ylam forward-substitution (which==1).
// Writes Lpan (panel float4 layout: [jb][i] = L[i][4jb..4jb+3]) + invd + ylam.
__global__ __launch_bounds__(512) void k_chol(const float* __restrict__ Kzzj, const float* __restrict__ KzzB,
    float* __restrict__ Lpan, float* __restrict__ invd,
    const float* __restrict__ LamU, float* __restrict__ ylam)
{
  int which = blockIdx.x & 1, c = blockIdx.x >> 1;
  const float* Ain = (which ? KzzB : Kzzj) + c*MZ*MZ;
  float4* LpB = (float4*)(Lpan + (size_t)(which*CC + c)*MZ*MZ);
  float* invB = invd + (which*CC + c)*MZ;
  __shared__ float As[MZ*MZ];    // col-major; input symmetric so straight copy is fine
  __shared__ float4 pan[MZ];     // scaled panel (separate object -> no alias with As)
  __shared__ float bs[MZ];       // running RHS residual for ylam
  __shared__ float ys[MZ];       // ylam solution
  int tid = threadIdx.x;
  int i = tid & 127, kh = tid >> 7;   // kh in 0..3
  {
    float4* d4 = (float4*)As; const float4* s4 = (const float4*)Ain;
    for (int idx = tid; idx < MZ*MZ/4; idx += 512) d4[idx] = s4[idx];
  }
  if (tid < MZ) bs[tid] = which ? LamU[c*MZ + tid] : 0.0f;
  __syncthreads();
  for (int j = 0; j < MZ; j += 4) {
    // raw (post-update) values of current 4 columns at own row + diag block + rhs
    float r0 = As[(j+0)*MZ + i], r1 = As[(j+1)*MZ + i], r2 = As[(j+2)*MZ + i], r3 = As[(j+3)*MZ + i];
    float a00 = As[j*MZ+j];
    float a10 = As[j*MZ+j+1], a20 = As[j*MZ+j+2], a30 = As[j*MZ+j+3];
    float a11 = As[(j+1)*MZ+j+1], a21 = As[(j+1)*MZ+j+2], a31 = As[(j+1)*MZ+j+3];
    float a22 = As[(j+2)*MZ+j+2], a32 = As[(j+2)*MZ+j+3];
    float a33 = As[(j+3)*MZ+j+3];
    float bj0 = bs[j], bj1 = bs[j+1], bj2 = bs[j+2], bj3 = bs[j+3];
    float d0 = sqrtf(a00), id0 = 1.0f/d0;
    float l10 = a10*id0, l20 = a20*id0, l30 = a30*id0;
    float d1 = sqrtf(a11 - l10*l10), id1 = 1.0f/d1;
    float l21 = (a21 - l20*l10)*id1, l31 = (a31 - l30*l10)*id1;
    float d2 = sqrtf(a22 - l20*l20 - l21*l21), id2 = 1.0f/d2;
    float l32 = (a32 - l30*l20 - l31*l21)*id2;
    float d3 = sqrtf(a33 - l30*l30 - l31*l31 - l32*l32), id3 = 1.0f/d3;
    float c0 = r0*id0;
    float c1 = (r1 - c0*l10)*id1;
    float c2 = (r2 - c0*l20 - c1*l21)*id2;
    float c3 = (r3 - c0*l30 - c1*l31 - c2*l32)*id3;
    // ylam chain (identical recurrence, one extra "column")
    float y0 = bj0*id0;
    float y1 = (bj1 - l10*y0)*id1;
    float y2 = (bj2 - l20*y0 - l21*y1)*id2;
    float y3 = (bj3 - l30*y0 - l31*y1 - l32*y2)*id3;
    if (kh == 0) {
      pan[i] = make_float4(c0, c1, c2, c3);
      LpB[(j>>2)*MZ + i] = make_float4(c0, c1, c2, c3);
      if (i == j) {
        invB[j] = id0; invB[j+1] = id1; invB[j+2] = id2; invB[j+3] = id3;
        ys[j] = y0; ys[j+1] = y1; ys[j+2] = y2; ys[j+3] = y3;
      }
      if (i >= j+4) bs[i] -= c0*y0 + c1*y1 + c2*y2 + c3*y3;   // thread-local c = L[i][j..j+3]
    }
    __syncthreads();   // pan visible; bs updates done
    // trailing rank-4 update, batched 8-wide (loads pipeline; pan!=As so no alias stall)
    for (int kb = j + 4 + kh; kb < MZ; kb += 32) {
      float4 pv[8]; float av[8];
      #pragma unroll
      for (int q = 0; q < 8; ++q) {
        int k = kb + 4*q;
        if (k < MZ) { pv[q] = pan[k]; av[q] = As[k*MZ + i]; }
      }
      #pragma unroll
      for (int q = 0; q < 8; ++q) {
        int k = kb + 4*q;
        if (k < MZ) As[k*MZ + i] = av[q] - (c0*pv[q].x + c1*pv[q].y + c2*pv[q].z + c3*pv[q].w);
      }
    }
    __syncthreads();   // trailing writes visible before next step's reads
  }
  if (which && tid < MZ) ylam[c*MZ + tid] = ys[tid];
}

// Forward substitution L W = Kzxt, 64 RHS columns per block, single wave, no barriers.
// grid 40 = (c, which, colhalf). Accumulates sum(W^2) and (which==1) f_mean = W . ylam.
__global__ __launch_bounds__(64) void k_subst(const float* __restrict__ Kxz,
    const float* __restrict__ Lpan, const float* __restrict__ invd,
    const float* __restrict__ ylam, float* __restrict__ ssq, float* __restrict__ fmean)
{
  int half  = blockIdx.x & 1;
  int which = (blockIdx.x >> 1) & 1;
  int c     = blockIdx.x >> 2;
  const float4* LpB = (const float4*)(Lpan + (size_t)(which*CC + c)*MZ*MZ);
  const float*  invB = invd + (which*CC + c)*MZ;
  const float*  ylB  = ylam + c*MZ;
  int lane = threadIdx.x;
  int tt = half*64 + lane;
  __shared__ float  Bs[MZ*64];     // 32 KiB, column per lane, stride 64 (conflict-free)
  __shared__ float4 Pp[2][MZ];     // double-buffered L panel (separate object from Bs)
  __shared__ float  invS[MZ], ylS[MZ];
  invS[lane] = invB[lane]; invS[64+lane] = invB[64+lane];
  ylS[lane]  = ylB[lane];  ylS[64+lane]  = ylB[64+lane];
  // load column tt of Kzxt = row tt of Kxz[c]
  const float4* src = (const float4*)(Kxz + (size_t)c*TN*MZ + (size_t)tt*MZ);
  #pragma unroll 4
  for (int i4 = 0; i4 < MZ/4; ++i4) {
    float4 v = src[i4];
    Bs[(4*i4+0)*64 + lane] = v.x;
    Bs[(4*i4+1)*64 + lane] = v.y;
    Bs[(4*i4+2)*64 + lane] = v.z;
    Bs[(4*i4+3)*64 + lane] = v.w;
  }
  Pp[0][lane]    = LpB[lane];
  Pp[0][64+lane] = LpB[64+lane];
  int cur = 0;
  float sq = 0.0f, fm = 0.0f;
  for (int jb = 0; jb < MZ/4; ++jb) {
    int j = jb*4;
    float4 pf0 = {0,0,0,0}, pf1 = {0,0,0,0};
    if (jb < MZ/4 - 1) { pf0 = LpB[(jb+1)*MZ + lane]; pf1 = LpB[(jb+1)*MZ + 64 + lane]; }
    float4 q1 = Pp[cur][j+1], q2 = Pp[cur][j+2], q3 = Pp[cur][j+3];
    float i0 = invS[j], i1 = invS[j+1], i2 = invS[j+2], i3 = invS[j+3];
    float b0 = Bs[(j+0)*64+lane], b1 = Bs[(j+1)*64+lane], b2 = Bs[(j+2)*64+lane], b3 = Bs[(j+3)*64+lane];
    float y0 = b0*i0;
    float y1 = (b1 - q1.x*y0)*i1;
    float y2 = (b2 - q2.x*y0 - q2.y*y1)*i2;
    float y3 = (b3 - q3.x*y0 - q3.y*y1 - q3.z*y2)*i3;
    sq += y0*y0 + y1*y1 + y2*y2 + y3*y3;
    fm += y0*ylS[j] + y1*ylS[j+1] + y2*ylS[j+2] + y3*ylS[j+3];
    // trailing update, batched 8-wide so LDS loads pipeline ahead of stores
    for (int ib = j + 4; ib < MZ; ib += 8) {
      float4 pv[8]; float bv[8];
      #pragma unroll
      for (int q = 0; q < 8; ++q) {
        int i = ib + q;
        if (i < MZ) { pv[q] = Pp[cur][i]; bv[q] = Bs[i*64 + lane]; }
      }
      #pragma unroll
      for (int q = 0; q < 8; ++q) {
        int i = ib + q;
        if (i < MZ) Bs[i*64 + lane] = bv[q] - (pv[q].x*y0 + pv[q].y*y1 + pv[q].z*y2 + pv[q].w*y3);
      }
    }
    if (jb < MZ/4 - 1) { Pp[cur^1][lane] = pf0; Pp[cur^1][64+lane] = pf1; }
    cur ^= 1;
  }
  ssq[(which*CC + c)*TN + tt] = sq;
  if (which) fmean[c*TN + tt] = fm;
}

// out[0][t][c] = f_mean ; out[1][t][c] = f_var.T = Kxx - sum(Am^2) + sum(Ab^2)
__global__ __launch_bounds__(256) void k_final(const float* __restrict__ fmean, const float* __restrict__ Kxxd,
    const float* __restrict__ ssq, float* __restrict__ out)
{
  int idx = blockIdx.x*256 + threadIdx.x;
  if (idx >= TN*CC) return;
  int t = idx / CC, c = idx % CC;
  out[idx] = fmean[c*TN + t];
  out[TN*CC + idx] = Kxxd[c*TN + t] - ssq[c*TN + t] + ssq[CC*TN + c*TN + t];
}

extern "C" void kernel_launch(void* const* d_in, const int* in_sizes, int n_in,
                              void* d_out, int out_size, void* d_ws, size_t ws_size,
                              hipStream_t stream) {
  (void)in_sizes; (void)n_in; (void)out_size; (void)ws_size;
  const float* X  = (const float*)d_in[0];
  const float* Y  = (const float*)d_in[1];
  const float* Z  = (const float*)d_in[2];
  const float* Xt = (const float*)d_in[3];
  const float* W1 = (const float*)d_in[4];
  const float* b1 = (const float*)d_in[5];
  const float* W2 = (const float*)d_in[6];
  const float* b2 = (const float*)d_in[7];
  const float* W3 = (const float*)d_in[8];
  float* ws  = (float*)d_ws;
  float* out = (float*)d_out;

  float* XS   = ws + OFF_XS;
  float* A1   = ws + OFF_A1;
  float* A2   = ws + OFF_A2;
  float* G1   = ws + OFF_G1;
  float* G2   = ws + OFF_G2;
  float* W2T  = ws + OFF_W2T;
  float* Base = ws + OFF_BASE;
  float* Kzx  = ws + OFF_KZX;
  float* Kzz  = ws + OFF_KZZ;
  float* Kxz  = ws + OFF_KXZ;
  float* Kxxd = ws + OFF_KXXD;
  float* Kzzj = ws + OFF_KZZJ;
  float* KzzB = ws + OFF_KZZB;
  float* LamU = ws + OFF_LAMU;
  float* Lpan = ws + OFF_LPAN;
  float* invd = ws + OFF_INVD;
  float* ylam = ws + OFF_YLAM;
  float* ssq  = ws + OFF_SSQ;
  float* fmean= ws + OFF_FMEAN;

  k_w2t<<<128, 128, 0, stream>>>(W2, W2T, LamU);
  k_features<<<S_TOT, 128, 0, stream>>>(X, Z, Xt, W1, b1, W2, b2, W3, W2T, XS, A1, A2, G1, G2);
  k_base<<<dim3(16, 8, 3), 256, 0, stream>>>(XS, A1, A2, Base);
  k_gram<<<dim3(16, 8, 3*CC), 256, 0, stream>>>(G1, G2, Base, Y, Kzx, Kzz, Kxz, LamU);
  k_kxxd<<<TN, 128, 0, stream>>>(XS, A1, A2, G1, G2, Kxxd);
  k_kzzb<<<dim3(8, 8, CC), 256, 0, stream>>>(Kzx, Kzz, Kzzj, KzzB);
  k_chol<<<2*CC, 512, 0, stream>>>(Kzzj, KzzB, Lpan, invd, LamU, ylam);
  k_subst<<<4*CC, 64, 0, stream>>>(Kxz, Lpan, invd, ylam, ssq, fmean);
  k_final<<<(TN*CC + 255)/256, 256, 0, stream>>>(fmean, Kxxd, ssq, out);
}

// Round 4
// 212.639 us; speedup vs baseline: 1.9791x; 1.3549x over previous
//
#include <hip/hip_runtime.h>

// NTK-SVGP forward: D=H=128, C=10, N=256, M=128, T=128, sigma2=1, delta=1
#define H 128
#define DD 128
#define CC 10
#define NX 256
#define MZ 128
#define TN 128
#define S_TOT 512   // samples: X[0..255], Z[256..383], X_test[384..511]
#define SCALE (1.0f/256.0f)   // 1/(delta*N)
#define JIT 1e-3f
#define INV_S2 1.0f

// ---------------- ws layout (float offsets) ----------------
#define OFF_XS    0u
#define OFF_A1    (OFF_XS   + S_TOT*DD)
#define OFF_A2    (OFF_A1   + S_TOT*H)
#define OFF_G1    (OFF_A2   + S_TOT*H)
#define OFF_G2    (OFF_G1   + S_TOT*CC*H)
#define OFF_W2T   (OFF_G2   + S_TOT*CC*H)
#define OFF_BASE  (OFF_W2T  + H*H)
#define BASE_ZX   0u
#define BASE_ZZ   (3u*MZ*NX)
#define BASE_TZ   (3u*MZ*NX + 3u*MZ*MZ)
#define OFF_KZX   (OFF_BASE + 3u*MZ*NX + 3u*MZ*MZ + 3u*TN*MZ)
#define OFF_KZZ   (OFF_KZX  + CC*MZ*NX)
#define OFF_KXZ   (OFF_KZZ  + CC*MZ*MZ)
#define OFF_KXXD  (OFF_KXZ  + CC*TN*MZ)
#define OFF_KZZJ  (OFF_KXXD + CC*TN)
#define OFF_KZZB  (OFF_KZZJ + CC*MZ*MZ)
#define OFF_LAMU  (OFF_KZZB + CC*MZ*MZ)
#define OFF_LPAN  (OFF_LAMU + CC*MZ)
#define OFF_INVD  (OFF_LPAN + 2u*CC*MZ*MZ)
#define OFF_YLAM  (OFF_INVD + 2u*CC*MZ)
#define OFF_SSQ   (OFF_YLAM + CC*MZ)
#define OFF_FMEAN (OFF_SSQ  + 2u*CC*TN)

__global__ __launch_bounds__(128) void k_w2t(const float* __restrict__ W2, float* __restrict__ W2T,
                                             float* __restrict__ LamU) {
  int k = blockIdx.x, h = threadIdx.x;
  W2T[k*H + h] = W2[h*H + k];
  if (k < CC) LamU[k*MZ + h] = 0.0f;   // zero for k_gram's atomic accumulation
}

// Per-sample forward + backprop features. One block per sample, 128 threads.
__global__ __launch_bounds__(128) void k_features(
    const float* __restrict__ X, const float* __restrict__ Z, const float* __restrict__ Xt,
    const float* __restrict__ W1, const float* __restrict__ b1,
    const float* __restrict__ W2, const float* __restrict__ b2,
    const float* __restrict__ W3, const float* __restrict__ W2T,
    float* __restrict__ XS, float* __restrict__ A1, float* __restrict__ A2,
    float* __restrict__ G1, float* __restrict__ G2)
{
  int s = blockIdx.x, h = threadIdx.x;
  const float* xin = (s < NX) ? X + s*DD : (s < NX+MZ ? Z + (s-NX)*DD : Xt + (s-NX-MZ)*DD);
  __shared__ float xs[DD], a1s[H], g2s[CC*H];
  float xv = xin[h];
  xs[h] = xv; XS[s*DD + h] = xv;
  __syncthreads();
  float acc = b1[h];
  #pragma unroll 4
  for (int d0 = 0; d0 < DD; ++d0) acc += xs[d0] * W1[d0*H + h];   // coalesced over h
  float a1 = tanhf(acc);
  a1s[h] = a1; A1[s*H + h] = a1;
  __syncthreads();
  acc = b2[h];
  #pragma unroll 4
  for (int d0 = 0; d0 < H; ++d0) acc += a1s[d0] * W2[d0*H + h];
  float a2 = tanhf(acc);
  A2[s*H + h] = a2;
  float t2 = 1.0f - a2*a2;
  #pragma unroll
  for (int c = 0; c < CC; ++c) {
    float g2 = W3[h*CC + c] * t2;
    g2s[c*H + h] = g2;
    G2[(s*CC + c)*H + h] = g2;
  }
  __syncthreads();
  float t1 = 1.0f - a1*a1;
  float accs[CC];
  #pragma unroll
  for (int c = 0; c < CC; ++c) accs[c] = 0.0f;
  for (int k = 0; k < H; ++k) {
    float w = W2T[k*H + h];        // coalesced over h
    #pragma unroll
    for (int c = 0; c < CC; ++c) accs[c] += w * g2s[c*H + k];   // broadcast
  }
  #pragma unroll
  for (int c = 0; c < CC; ++c) G1[(s*CC + c)*H + h] = t1 * accs[c];
}

// Class-independent base dot products: 1+x.x', 1+a1.a1', 1+a2.a2'
__global__ __launch_bounds__(256) void k_base(const float* __restrict__ XS,
    const float* __restrict__ A1, const float* __restrict__ A2, float* __restrict__ Base)
{
  int set = blockIdx.z;
  int colsN = (set == 0) ? NX : MZ;
  if ((int)blockIdx.x * 16 >= colsN) return;
  int rowOff = (set == 2) ? NX+MZ : NX;
  int colOff = (set == 0) ? 0 : NX;
  unsigned baseOff = (set == 0) ? BASE_ZX : (set == 1 ? BASE_ZZ : BASE_TZ);
  __shared__ float rx[16*132], r1[16*132], r2[16*132], cxs[16*132], c1s[16*132], c2s[16*132];
  int tid = threadIdx.x, m0 = blockIdx.y*16, n0 = blockIdx.x*16;
  for (int idx = tid; idx < 16*128; idx += 256) {
    int r = idx >> 7, hh = idx & 127;
    int sr = rowOff + m0 + r, sc = colOff + n0 + r;
    rx [r*132+hh] = XS[sr*DD+hh]; r1[r*132+hh] = A1[sr*H+hh]; r2[r*132+hh] = A2[sr*H+hh];
    cxs[r*132+hh] = XS[sc*DD+hh]; c1s[r*132+hh] = A1[sc*H+hh]; c2s[r*132+hh] = A2[sc*H+hh];
  }
  __syncthreads();
  int ty = tid >> 4, tx = tid & 15;
  const float4* pa = (const float4*)(rx  + ty*132);
  const float4* pb = (const float4*)(cxs + tx*132);
  const float4* pc = (const float4*)(r1  + ty*132);
  const float4* pd = (const float4*)(c1s + tx*132);
  const float4* pe = (const float4*)(r2  + ty*132);
  const float4* pf = (const float4*)(c2s + tx*132);
  float d0 = 0, d1 = 0, d2 = 0;
  #pragma unroll 8
  for (int q = 0; q < 32; ++q) {
    float4 a = pa[q], b = pb[q]; d0 += a.x*b.x + a.y*b.y + a.z*b.z + a.w*b.w;
    float4 c = pc[q], d = pd[q]; d1 += c.x*d.x + c.y*d.y + c.z*d.z + c.w*d.w;
    float4 e = pe[q], f = pf[q]; d2 += e.x*f.x + e.y*f.y + e.z*f.z + e.w*f.w;
  }
  int m = m0 + ty, n = n0 + tx;
  float* Bp = Base + baseOff;
  int area = 128 * colsN;
  Bp[0*area + m*colsN + n] = 1.0f + d0;
  Bp[1*area + m*colsN + n] = 1.0f + d1;
  Bp[2*area + m*colsN + n] = 1.0f + d2;
}

// Per-class NTK gram: K = SCALE*(B0*(g1.g1') + B1*(g2.g2') + B2)
// set==0 additionally folds LamU[c][m] += sum_n Kzx[m][n]*Y[n][c] via shuffles+atomics.
__global__ __launch_bounds__(256) void k_gram(const float* __restrict__ G1, const float* __restrict__ G2,
    const float* __restrict__ Base, const float* __restrict__ Y,
    float* __restrict__ Kzx, float* __restrict__ Kzz, float* __restrict__ Kxz,
    float* __restrict__ LamU)
{
  int z = blockIdx.z, set = z / CC, c = z % CC;
  int colsN = (set == 0) ? NX : MZ;
  if ((int)blockIdx.x * 16 >= colsN) return;
  int rowOff = (set == 2) ? NX+MZ : NX;
  int colOff = (set == 0) ? 0 : NX;
  unsigned baseOff = (set == 0) ? BASE_ZX : (set == 1 ? BASE_ZZ : BASE_TZ);
  float* outp = (set == 0) ? Kzx + c*MZ*NX : (set == 1 ? Kzz + c*MZ*MZ : Kxz + c*TN*MZ);
  __shared__ float g1r[16*132], g2r[16*132], g1c[16*132], g2c[16*132];
  int tid = threadIdx.x, m0 = blockIdx.y*16, n0 = blockIdx.x*16;
  for (int idx = tid; idx < 2048; idx += 256) {
    int r = idx >> 7, hh = idx & 127;
    int sr = rowOff + m0 + r, sc = colOff + n0 + r;
    g1r[r*132+hh] = G1[(sr*CC + c)*H + hh]; g2r[r*132+hh] = G2[(sr*CC + c)*H + hh];
    g1c[r*132+hh] = G1[(sc*CC + c)*H + hh]; g2c[r*132+hh] = G2[(sc*CC + c)*H + hh];
  }
  __syncthreads();
  int ty = tid >> 4, tx = tid & 15;
  const float4* p1 = (const float4*)(g1r + ty*132);
  const float4* p2 = (const float4*)(g1c + tx*132);
  const float4* p3 = (const float4*)(g2r + ty*132);
  const float4* p4 = (const float4*)(g2c + tx*132);
  float dg1 = 0, dg2 = 0;
  #pragma unroll 8
  for (int q = 0; q < 32; ++q) {
    float4 a = p1[q], b = p2[q]; dg1 += a.x*b.x + a.y*b.y + a.z*b.z + a.w*b.w;
    float4 e = p3[q], f = p4[q]; dg2 += e.x*f.x + e.y*f.y + e.z*f.z + e.w*f.w;
  }
  int m = m0 + ty, n = n0 + tx;
  const float* Bp = Base + baseOff;
  int area = 128 * colsN;
  float b0 = Bp[m*colsN + n], b1v = Bp[area + m*colsN + n], b2v = Bp[2*area + m*colsN + n];
  float val = SCALE * (b0*dg1 + b1v*dg2 + b2v);
  outp[m*colsN + n] = val;
  if (set == 0) {
    float lam = val * Y[n*CC + c] * INV_S2;
    lam += __shfl_xor(lam, 1, 64); lam += __shfl_xor(lam, 2, 64);
    lam += __shfl_xor(lam, 4, 64); lam += __shfl_xor(lam, 8, 64);
    if (tx == 0) atomicAdd(&LamU[c*MZ + m], lam);
  }
}

__device__ __forceinline__ float blockReduce128(float v, float* red, int h) {
  #pragma unroll
  for (int off = 32; off > 0; off >>= 1) v += __shfl_down(v, off, 64);
  if ((h & 63) == 0) red[h >> 6] = v;
  __syncthreads();
  float r = red[0] + red[1];
  __syncthreads();
  return r;
}

// Kxx_diag[c][t]; one block per test sample.
__global__ __launch_bounds__(128) void k_kxxd(const float* __restrict__ XS, const float* __restrict__ A1,
    const float* __restrict__ A2, const float* __restrict__ G1, const float* __restrict__ G2,
    float* __restrict__ Kxxd)
{
  int t = blockIdx.x, h = threadIdx.x, s = NX + MZ + t;
  __shared__ float red[2];
  float xv = XS[s*DD+h], a1v = A1[s*H+h], a2v = A2[s*H+h];
  float nx  = blockReduce128(xv*xv,  red, h);
  float na1 = blockReduce128(a1v*a1v, red, h);
  float na2 = blockReduce128(a2v*a2v, red, h);
  for (int c = 0; c < CC; ++c) {
    float g1 = G1[(s*CC+c)*H+h], g2 = G2[(s*CC+c)*H+h];
    float n1 = blockReduce128(g1*g1, red, h);
    float n2 = blockReduce128(g2*g2, red, h);
    if (h == 0) Kxxd[c*TN + t] = SCALE * ((1.0f+nx)*n1 + (1.0f+na1)*n2 + (1.0f+na2));
  }
}

// KzzB = Kzz + Kzx Kzx^T / sigma2 + 2*JIT*I ; Kzzj = Kzz + JIT*I
__global__ __launch_bounds__(256) void k_kzzb(const float* __restrict__ Kzx, const float* __restrict__ Kzz,
    float* __restrict__ Kzzj, float* __restrict__ KzzB)
{
  int c = blockIdx.z, m0 = blockIdx.y*16, k0 = blockIdx.x*16;
  int tid = threadIdx.x, ty = tid >> 4, tx = tid & 15;
  __shared__ float Am[16*17], Ak[16*17];
  const float* Kc = Kzx + c*MZ*NX;
  float acc = 0;
  for (int nc = 0; nc < NX; nc += 16) {
    Am[ty*17+tx] = Kc[(m0+ty)*NX + nc + tx];
    Ak[ty*17+tx] = Kc[(k0+ty)*NX + nc + tx];
    __syncthreads();
    #pragma unroll
    for (int p = 0; p < 16; ++p) acc += Am[ty*17+p] * Ak[tx*17+p];
    __syncthreads();
  }
  int m = m0+ty, k = k0+tx, idx = c*MZ*MZ + m*MZ + k;
  float kzz = Kzz[idx];
  float dia = (m == k) ? 1.0f : 0.0f;
  Kzzj[idx] = kzz + dia*JIT;
  KzzB[idx] = kzz + acc*INV_S2 + dia*2.0f*JIT;
}

// Blocked (rank-4) Cholesky, in-LDS, col-major. Alias-free trailing update via separate
// pan[] array + 8-wide batched rmw. Folds the ylam forward-substitution (which==1).
// Writes Lpan (panel float4 layout: [jb][i] = L[i][4jb..4jb+3]) + invd + ylam.
__global__ __launch_bounds__(512) void k_chol(const float* __restrict__ Kzzj, const float* __restrict__ KzzB,
    float* __restrict__ Lpan, float* __restrict__ invd,
    const float* __restrict__ LamU, float* __restrict__ ylam)
{
  int which = blockIdx.x & 1, c = blockIdx.x >> 1;
  const float* Ain = (which ? KzzB : Kzzj) + c*MZ*MZ;
  float4* LpB = (float4*)(Lpan + (size_t)(which*CC + c)*MZ*MZ);
  float* invB = invd + (which*CC + c)*MZ;
  __shared__ float As[MZ*MZ];    // col-major; input symmetric so straight copy is fine
  __shared__ float4 pan[MZ];     // scaled panel (separate object -> no alias with As)
  __shared__ float bs[MZ];       // running RHS residual for ylam
  __shared__ float ys[MZ];       // ylam solution
  int tid = threadIdx.x;
  int i = tid & 127, kh = tid >> 7;   // kh in 0..3
  {
    float4* d4 = (float4*)As; const float4* s4 = (const float4*)Ain;
    for (int idx = tid; idx < MZ*MZ/4; idx += 512) d4[idx] = s4[idx];
  }
  if (tid < MZ) bs[tid] = which ? LamU[c*MZ + tid] : 0.0f;
  __syncthreads();
  for (int j = 0; j < MZ; j += 4) {
    // raw (post-update) values of current 4 columns at own row + diag block + rhs
    float r0 = As[(j+0)*MZ + i], r1 = As[(j+1)*MZ + i], r2 = As[(j+2)*MZ + i], r3 = As[(j+3)*MZ + i];
    float a00 = As[j*MZ+j];
    float a10 = As[j*MZ+j+1], a20 = As[j*MZ+j+2], a30 = As[j*MZ+j+3];
    float a11 = As[(j+1)*MZ+j+1], a21 = As[(j+1)*MZ+j+2], a31 = As[(j+1)*MZ+j+3];
    float a22 = As[(j+2)*MZ+j+2], a32 = As[(j+2)*MZ+j+3];
    float a33 = As[(j+3)*MZ+j+3];
    float bj0 = bs[j], bj1 = bs[j+1], bj2 = bs[j+2], bj3 = bs[j+3];
    float d0 = sqrtf(a00), id0 = 1.0f/d0;
    float l10 = a10*id0, l20 = a20*id0, l30 = a30*id0;
    float d1 = sqrtf(a11 - l10*l10), id1 = 1.0f/d1;
    float l21 = (a21 - l20*l10)*id1, l31 = (a31 - l30*l10)*id1;
    float d2 = sqrtf(a22 - l20*l20 - l21*l21), id2 = 1.0f/d2;
    float l32 = (a32 - l30*l20 - l31*l21)*id2;
    float d3 = sqrtf(a33 - l30*l30 - l31*l31 - l32*l32), id3 = 1.0f/d3;
    float c0 = r0*id0;
    float c1 = (r1 - c0*l10)*id1;
    float c2 = (r2 - c0*l20 - c1*l21)*id2;
    float c3 = (r3 - c0*l30 - c1*l31 - c2*l32)*id3;
    // ylam chain (identical recurrence, one extra "column")
    float y0 = bj0*id0;
    float y1 = (bj1 - l10*y0)*id1;
    float y2 = (bj2 - l20*y0 - l21*y1)*id2;
    float y3 = (bj3 - l30*y0 - l31*y1 - l32*y2)*id3;
    if (kh == 0) {
      pan[i] = make_float4(c0, c1, c2, c3);
      LpB[(j>>2)*MZ + i] = make_float4(c0, c1, c2, c3);
      if (i == j) {
        invB[j] = id0; invB[j+1] = id1; invB[j+2] = id2; invB[j+3] = id3;
        ys[j] = y0; ys[j+1] = y1; ys[j+2] = y2; ys[j+3] = y3;
      }
      if (i >= j+4) bs[i] -= c0*y0 + c1*y1 + c2*y2 + c3*y3;   // thread-local c = L[i][j..j+3]
    }
    __syncthreads();   // pan visible; bs updates done
    // trailing rank-4 update, batched 8-wide (loads pipeline; pan!=As so no alias stall)
    for (int kb = j + 4 + kh; kb < MZ; kb += 32) {
      float4 pv[8]; float av[8];
      #pragma unroll
      for (int q = 0; q < 8; ++q) {
        int k = kb + 4*q;
        if (k < MZ) { pv[q] = pan[k]; av[q] = As[k*MZ + i]; }
      }
      #pragma unroll
      for (int q = 0; q < 8; ++q) {
        int k = kb + 4*q;
        if (k < MZ) As[k*MZ + i] = av[q] - (c0*pv[q].x + c1*pv[q].y + c2*pv[q].z + c3*pv[q].w);
      }
    }
    __syncthreads();   // trailing writes visible before next step's reads
  }
  if (which && tid < MZ) ylam[c*MZ + tid] = ys[tid];
}

// Forward substitution L W = Kzxt, 64 RHS columns per block, single wave, no barriers.
// grid 40 = (c, which, colhalf). Accumulates sum(W^2) and (which==1) f_mean = W . ylam.
// (R2 form: simple trailing loop — pipelines fine; batching regressed it 16->137us.)
__global__ __launch_bounds__(64) void k_subst(const float* __restrict__ Kxz,
    const float* __restrict__ Lpan, const float* __restrict__ invd,
    const float* __restrict__ ylam, float* __restrict__ ssq, float* __restrict__ fmean)
{
  int half  = blockIdx.x & 1;
  int which = (blockIdx.x >> 1) & 1;
  int c     = blockIdx.x >> 2;
  const float4* LpB = (const float4*)(Lpan + (size_t)(which*CC + c)*MZ*MZ);
  const float*  invB = invd + (which*CC + c)*MZ;
  const float*  ylB  = ylam + c*MZ;
  int lane = threadIdx.x;
  int tt = half*64 + lane;
  __shared__ float  Bs[MZ*64];     // 32 KiB, column per lane, stride 64 (conflict-free)
  __shared__ float4 Pp[2][MZ];     // double-buffered L panel (separate object from Bs)
  __shared__ float  invS[MZ], ylS[MZ];
  invS[lane] = invB[lane]; invS[64+lane] = invB[64+lane];
  ylS[lane]  = ylB[lane];  ylS[64+lane]  = ylB[64+lane];
  // load column tt of Kzxt = row tt of Kxz[c]
  const float4* src = (const float4*)(Kxz + (size_t)c*TN*MZ + (size_t)tt*MZ);
  #pragma unroll 4
  for (int i4 = 0; i4 < MZ/4; ++i4) {
    float4 v = src[i4];
    Bs[(4*i4+0)*64 + lane] = v.x;
    Bs[(4*i4+1)*64 + lane] = v.y;
    Bs[(4*i4+2)*64 + lane] = v.z;
    Bs[(4*i4+3)*64 + lane] = v.w;
  }
  Pp[0][lane]    = LpB[lane];
  Pp[0][64+lane] = LpB[64+lane];
  int cur = 0;
  float sq = 0.0f, fm = 0.0f;
  for (int jb = 0; jb < MZ/4; ++jb) {
    int j = jb*4;
    float4 pf0 = {0,0,0,0}, pf1 = {0,0,0,0};
    if (jb < MZ/4 - 1) { pf0 = LpB[(jb+1)*MZ + lane]; pf1 = LpB[(jb+1)*MZ + 64 + lane]; }
    float4 q1 = Pp[cur][j+1], q2 = Pp[cur][j+2], q3 = Pp[cur][j+3];
    float i0 = invS[j], i1 = invS[j+1], i2 = invS[j+2], i3 = invS[j+3];
    float b0 = Bs[(j+0)*64+lane], b1 = Bs[(j+1)*64+lane], b2 = Bs[(j+2)*64+lane], b3 = Bs[(j+3)*64+lane];
    float y0 = b0*i0;
    float y1 = (b1 - q1.x*y0)*i1;
    float y2 = (b2 - q2.x*y0 - q2.y*y1)*i2;
    float y3 = (b3 - q3.x*y0 - q3.y*y1 - q3.z*y2)*i3;
    sq += y0*y0 + y1*y1 + y2*y2 + y3*y3;
    fm += y0*ylS[j] + y1*ylS[j+1] + y2*ylS[j+2] + y3*ylS[j+3];
    for (int i = j+4; i < MZ; ++i) {
      float4 lv = Pp[cur][i];                         // broadcast b128
      Bs[i*64+lane] -= lv.x*y0 + lv.y*y1 + lv.z*y2 + lv.w*y3;
    }
    if (jb < MZ/4 - 1) { Pp[cur^1][lane] = pf0; Pp[cur^1][64+lane] = pf1; }
    cur ^= 1;
  }
  ssq[(which*CC + c)*TN + tt] = sq;
  if (which) fmean[c*TN + tt] = fm;
}

// out[0][t][c] = f_mean ; out[1][t][c] = f_var.T = Kxx - sum(Am^2) + sum(Ab^2)
__global__ __launch_bounds__(256) void k_final(const float* __restrict__ fmean, const float* __restrict__ Kxxd,
    const float* __restrict__ ssq, float* __restrict__ out)
{
  int idx = blockIdx.x*256 + threadIdx.x;
  if (idx >= TN*CC) return;
  int t = idx / CC, c = idx % CC;
  out[idx] = fmean[c*TN + t];
  out[TN*CC + idx] = Kxxd[c*TN + t] - ssq[c*TN + t] + ssq[CC*TN + c*TN + t];
}

extern "C" void kernel_launch(void* const* d_in, const int* in_sizes, int n_in,
                              void* d_out, int out_size, void* d_ws, size_t ws_size,
                              hipStream_t stream) {
  (void)in_sizes; (void)n_in; (void)out_size; (void)ws_size;
  const float* X  = (const float*)d_in[0];
  const float* Y  = (const float*)d_in[1];
  const float* Z  = (const float*)d_in[2];
  const float* Xt = (const float*)d_in[3];
  const float* W1 = (const float*)d_in[4];
  const float* b1 = (const float*)d_in[5];
  const float* W2 = (const float*)d_in[6];
  const float* b2 = (const float*)d_in[7];
  const float* W3 = (const float*)d_in[8];
  float* ws  = (float*)d_ws;
  float* out = (float*)d_out;

  float* XS   = ws + OFF_XS;
  float* A1   = ws + OFF_A1;
  float* A2   = ws + OFF_A2;
  float* G1   = ws + OFF_G1;
  float* G2   = ws + OFF_G2;
  float* W2T  = ws + OFF_W2T;
  float* Base = ws + OFF_BASE;
  float* Kzx  = ws + OFF_KZX;
  float* Kzz  = ws + OFF_KZZ;
  float* Kxz  = ws + OFF_KXZ;
  float* Kxxd = ws + OFF_KXXD;
  float* Kzzj = ws + OFF_KZZJ;
  float* KzzB = ws + OFF_KZZB;
  float* LamU = ws + OFF_LAMU;
  float* Lpan = ws + OFF_LPAN;
  float* invd = ws + OFF_INVD;
  float* ylam = ws + OFF_YLAM;
  float* ssq  = ws + OFF_SSQ;
  float* fmean= ws + OFF_FMEAN;

  k_w2t<<<128, 128, 0, stream>>>(W2, W2T, LamU);
  k_features<<<S_TOT, 128, 0, stream>>>(X, Z, Xt, W1, b1, W2, b2, W3, W2T, XS, A1, A2, G1, G2);
  k_base<<<dim3(16, 8, 3), 256, 0, stream>>>(XS, A1, A2, Base);
  k_gram<<<dim3(16, 8, 3*CC), 256, 0, stream>>>(G1, G2, Base, Y, Kzx, Kzz, Kxz, LamU);
  k_kxxd<<<TN, 128, 0, stream>>>(XS, A1, A2, G1, G2, Kxxd);
  k_kzzb<<<dim3(8, 8, CC), 256, 0, stream>>>(Kzx, Kzz, Kzzj, KzzB);
  k_chol<<<2*CC, 512, 0, stream>>>(Kzzj, KzzB, Lpan, invd, LamU, ylam);
  k_subst<<<4*CC, 64, 0, stream>>>(Kxz, Lpan, invd, ylam, ssq, fmean);
  k_final<<<(TN*CC + 255)/256, 256, 0, stream>>>(fmean, Kxxd, ssq, out);
}